// Round 3
// baseline (1070.619 us; speedup 1.0000x reference)
//
#include <hip/hip_runtime.h>
#include <math.h>

// ---------------------------------------------------------------------------
// SimpleLESS4FDModel: 2-layer HGT on a homogeneous graph.
// a_rel / m_rel folded into projection weights (fold_weights).
// Per edge:  alpha = <kt[src], q[dst]>_head * p_rel / 4 ;
//   agg[dst] = sum_e exp(alpha) * vt[src] / (sum_e exp(alpha) + 1e-16)
// CSR (built once, reused by both layers) makes aggregation atomic-free.
//
// R1: no runtime-indexed local arrays (scratch). R2: bound unrolls, cap VGPRs.
// R3: fp32 vector GEMM LDS-pipe-bound -> split-bf16 MFMA (ah*bh+ah*bl+al*bh).
// R4: m97-style LDS-staged K-loop with depth-1 register prefetch (K=768 only).
// R5: edge_agg latency-bound -> interleaved kt/vt (one dwordx2/lane/edge) +
//     4-wide masked unroll + prescaled qv.
// R6: (a) edge_agg depth 8 MLP, scalarized CSR indices (readfirstlane ->
//     s_load + scalar gather bases), DPP row_ror rotation-reduce (VALU) in
//     place of shfl_xor (DS pipe). (b) K=64 GEMMs: flat single-stage kernel
//     (whole A + all CB col-blocks of B staged once, ONE barrier, no chunk
//     loop); qkv uses CB=3 so A is read once instead of 3x.
// R7: R6 bench was an infra failure (container acquire), not a kernel error;
//     resubmitting unchanged after a hazard audit (LDS exactly 64KB legal,
//     all loads in bounds, no divergent-exit loops).
// ---------------------------------------------------------------------------

typedef __attribute__((ext_vector_type(8))) short bf16x8;  // 8 bf16 (4 VGPRs)
typedef __attribute__((ext_vector_type(4))) float f32x4;

__device__ __forceinline__ float gelu_t(float x) {
  const float c = 0.7978845608028654f;  // sqrt(2/pi)
  float t = tanhf(c * (x + 0.044715f * x * x * x));
  return 0.5f * x * (1.0f + t);
}

// split fp32 -> bf16 hi (truncate) + bf16 lo (truncate of remainder)
__device__ __forceinline__ void split1(float a, ushort& h, ushort& l) {
  unsigned u = __float_as_uint(a);
  unsigned uh = u & 0xffff0000u;
  float fl = a - __uint_as_float(uh);
  h = (ushort)(uh >> 16);
  l = (ushort)(__float_as_uint(fl) >> 16);
}

// 16-lane rotation-reduce via DPP row_ror (rotations 1,2,4,8 span the cyclic
// group -> every lane ends with the full 16-lane sum). Pure VALU, no DS pipe.
template<int CTRL>
__device__ __forceinline__ float row_ror_add(float v) {
  int r = __builtin_amdgcn_update_dpp(0, __float_as_int(v), CTRL, 0xF, 0xF, true);
  return v + __int_as_float(r);
}
__device__ __forceinline__ float red16(float v) {
  v = row_ror_add<0x121>(v);  // ror 1
  v = row_ror_add<0x122>(v);  // ror 2
  v = row_ror_add<0x124>(v);  // ror 4
  v = row_ror_add<0x128>(v);  // ror 8
  return v;
}

// ---------------- split-bf16 MFMA GEMM, LDS-staged (K large, streaming) ------
// out[r, colBlk+c] = epi(A[r,:] @ W[:,c] + bias[c])
// Block: 256 threads = 4 waves; 64 rows x 64 cols per block.
// Wt layout (ushort): per colBlk cb, per 32-k chunk ch: 4096 ushorts =
//   [h: c(64) x k(32)] ++ [l: c(64) x k(32)]   (contiguous 8 KB per chunk)
template<int K, bool PRE_GELU, bool EPI_SKIP>
__global__ __launch_bounds__(256, 4)
void mfma_gemm(const float* __restrict__ A, int ldA,
               const ushort* __restrict__ Wt,
               const float* __restrict__ bias,
               const float* __restrict__ Hprev,
               const float* __restrict__ skipPtr,
               float* __restrict__ outp, int ldOut, int nRows)
{
  constexpr int NCH = K / 32;
  __shared__ ushort sA[2 * 64 * 32];  // h at 0, l at +2048 (8 KB)
  __shared__ ushort sB[2 * 64 * 32];  // h at 0, l at +2048 (8 KB)
  const int tid = threadIdx.x;
  const int lane = tid & 63;
  const int wv = tid >> 6;
  const int m = lane & 15;   // A row / B col / C col within tile
  const int q = lane >> 4;   // quad
  const int row0 = blockIdx.x * 64;
  const int colBlk = blockIdx.y * 64;

  // staging roles: thread t stages A row (t>>2), k-offset (t&3)*8 (32 B)
  const int srow = tid >> 2;
  const int skoff = (tid & 3) * 8;
  int gr = row0 + srow; if (gr >= nRows) gr = nRows - 1;  // clamp; masked at store
  const float* aBase = A + (size_t)gr * ldA + skoff;
  const float4* wBase = (const float4*)(Wt + (size_t)blockIdx.y * NCH * 4096);

  f32x4 acc[4];
#pragma unroll
  for (int ct = 0; ct < 4; ++ct) acc[ct] = (f32x4){0.f, 0.f, 0.f, 0.f};

  // prefetch chunk 0 into registers
  float4 a0 = *(const float4*)(aBase + 0);
  float4 a1 = *(const float4*)(aBase + 4);
  float4 b0 = wBase[tid * 2];
  float4 b1 = wBase[tid * 2 + 1];

#pragma clang loop unroll(disable)
  for (int ch = 0; ch < NCH; ++ch) {
    float4 na0 = a0, na1 = a1, nb0 = b0, nb1 = b1;
    if (ch + 1 < NCH) {  // issue next chunk's global loads before consuming cur
      na0 = *(const float4*)(aBase + (ch + 1) * 32);
      na1 = *(const float4*)(aBase + (ch + 1) * 32 + 4);
      const float4* wc = wBase + (size_t)(ch + 1) * 512;  // 4096 ushorts = 512 float4
      nb0 = wc[tid * 2];
      nb1 = wc[tid * 2 + 1];
    }
    // split current A (gelu once, at stage time)
    float av[8] = {a0.x, a0.y, a0.z, a0.w, a1.x, a1.y, a1.z, a1.w};
    if (PRE_GELU) {
#pragma unroll
      for (int j = 0; j < 8; ++j) av[j] = gelu_t(av[j]);
    }
    bf16x8 vh, vl;
#pragma unroll
    for (int j = 0; j < 8; ++j) {
      ushort h, l; split1(av[j], h, l);
      vh[j] = (short)h; vl[j] = (short)l;
    }
    __syncthreads();  // previous chunk's LDS reads complete before overwrite
    *(bf16x8*)(sA + srow * 32 + skoff) = vh;
    *(bf16x8*)(sA + 2048 + srow * 32 + skoff) = vl;
    ((float4*)sB)[tid * 2] = b0;
    ((float4*)sB)[tid * 2 + 1] = b1;
    __syncthreads();
    // fragments from LDS (all conflict-free b128 patterns) + 12 MFMAs
    bf16x8 ah = *(const bf16x8*)(sA + (wv * 16 + m) * 32 + q * 8);
    bf16x8 al = *(const bf16x8*)(sA + 2048 + (wv * 16 + m) * 32 + q * 8);
#pragma unroll
    for (int ct = 0; ct < 4; ++ct) {
      bf16x8 bh = *(const bf16x8*)(sB + (ct * 16 + m) * 32 + q * 8);
      bf16x8 bl = *(const bf16x8*)(sB + 2048 + (ct * 16 + m) * 32 + q * 8);
      acc[ct] = __builtin_amdgcn_mfma_f32_16x16x32_bf16(ah, bh, acc[ct], 0, 0, 0);
      acc[ct] = __builtin_amdgcn_mfma_f32_16x16x32_bf16(ah, bl, acc[ct], 0, 0, 0);
      acc[ct] = __builtin_amdgcn_mfma_f32_16x16x32_bf16(al, bh, acc[ct], 0, 0, 0);
    }
    a0 = na0; a1 = na1; b0 = nb0; b1 = nb1;
  }

  // epilogue: C/D layout col = lane&15 (=m), row = quad*4 + reg  [m89-verified]
  float g = 0.f, gi = 0.f;
  if (EPI_SKIP) { g = 1.0f / (1.0f + __expf(-skipPtr[0])); gi = 1.0f - g; }
#pragma unroll
  for (int ct = 0; ct < 4; ++ct) {
    int c = colBlk + ct * 16 + m;
    float b = bias[c];
#pragma unroll
    for (int i = 0; i < 4; ++i) {
      int r = row0 + wv * 16 + q * 4 + i;
      if (r < nRows) {
        float o = acc[ct][i] + b;
        if (EPI_SKIP) {
          float hp = Hprev[(size_t)r * 64 + c];
          o = fmaxf(g * o + gi * hp, 0.f);
        }
        outp[(size_t)r * ldOut + c] = o;
      }
    }
  }
}

// ---------------- flat K=64 GEMM: whole problem staged once, ONE barrier -----
// A is [nRows,64] fp32 (ld 64). Wt holds CB col-blocks in the chunked layout
// (region (cb*2+ch) of 4096 ushorts). LDS: sA 16KB + CB*16KB.
template<int CB, bool PRE_GELU, bool EPI_SKIP>
__global__ __launch_bounds__(256, 2)
void mfma_gemm_k64(const float* __restrict__ A,
                   const ushort* __restrict__ Wt,
                   const float* __restrict__ bias,
                   const float* __restrict__ Hprev,
                   const float* __restrict__ skipPtr,
                   float* __restrict__ outp, int ldOut, int nRows)
{
  __shared__ ushort sA[2 * 4096];        // [ch][h(2048) ++ l(2048)]
  __shared__ ushort sB[CB][2 * 4096];
  const int tid = threadIdx.x;
  const int lane = tid & 63;
  const int wv = tid >> 6;
  const int m = lane & 15;
  const int q = lane >> 4;
  const int row0 = blockIdx.x * 64;
  const int srow = tid >> 2;
  const int skoff = (tid & 3) * 8;
  int gr = row0 + srow; if (gr >= nRows) gr = nRows - 1;
  const float* aBase = A + (size_t)gr * 64 + skoff;
  const float4* wBase = (const float4*)Wt;

  // issue ALL global loads up front
  float4 a0 = *(const float4*)(aBase + 0);
  float4 a1 = *(const float4*)(aBase + 4);
  float4 a2 = *(const float4*)(aBase + 32);
  float4 a3 = *(const float4*)(aBase + 36);
  float4 bb0[CB], bb1[CB], bb2[CB], bb3[CB];
#pragma unroll
  for (int cb = 0; cb < CB; ++cb) {
    bb0[cb] = wBase[(size_t)(cb * 2 + 0) * 512 + tid * 2];
    bb1[cb] = wBase[(size_t)(cb * 2 + 0) * 512 + tid * 2 + 1];
    bb2[cb] = wBase[(size_t)(cb * 2 + 1) * 512 + tid * 2];
    bb3[cb] = wBase[(size_t)(cb * 2 + 1) * 512 + tid * 2 + 1];
  }

  // split + store A (both 32-k chunks)
  {
    float av[16] = {a0.x, a0.y, a0.z, a0.w, a1.x, a1.y, a1.z, a1.w,
                    a2.x, a2.y, a2.z, a2.w, a3.x, a3.y, a3.z, a3.w};
    if (PRE_GELU) {
#pragma unroll
      for (int j = 0; j < 16; ++j) av[j] = gelu_t(av[j]);
    }
    bf16x8 vh0, vl0, vh1, vl1;
#pragma unroll
    for (int j = 0; j < 8; ++j) {
      ushort h, l; split1(av[j], h, l);
      vh0[j] = (short)h; vl0[j] = (short)l;
    }
#pragma unroll
    for (int j = 0; j < 8; ++j) {
      ushort h, l; split1(av[8 + j], h, l);
      vh1[j] = (short)h; vl1[j] = (short)l;
    }
    *(bf16x8*)(sA + srow * 32 + skoff) = vh0;
    *(bf16x8*)(sA + 2048 + srow * 32 + skoff) = vl0;
    *(bf16x8*)(sA + 4096 + srow * 32 + skoff) = vh1;
    *(bf16x8*)(sA + 4096 + 2048 + srow * 32 + skoff) = vl1;
  }
#pragma unroll
  for (int cb = 0; cb < CB; ++cb) {
    ((float4*)(sB[cb]))[tid * 2] = bb0[cb];
    ((float4*)(sB[cb]))[tid * 2 + 1] = bb1[cb];
    ((float4*)(sB[cb] + 4096))[tid * 2] = bb2[cb];
    ((float4*)(sB[cb] + 4096))[tid * 2 + 1] = bb3[cb];
  }
  __syncthreads();

  f32x4 acc[CB][4];
#pragma unroll
  for (int cb = 0; cb < CB; ++cb)
#pragma unroll
    for (int ct = 0; ct < 4; ++ct) acc[cb][ct] = (f32x4){0.f, 0.f, 0.f, 0.f};

  bf16x8 ah0 = *(const bf16x8*)(sA + (wv * 16 + m) * 32 + q * 8);
  bf16x8 al0 = *(const bf16x8*)(sA + 2048 + (wv * 16 + m) * 32 + q * 8);
  bf16x8 ah1 = *(const bf16x8*)(sA + 4096 + (wv * 16 + m) * 32 + q * 8);
  bf16x8 al1 = *(const bf16x8*)(sA + 4096 + 2048 + (wv * 16 + m) * 32 + q * 8);
#pragma unroll
  for (int cb = 0; cb < CB; ++cb) {
#pragma unroll
    for (int ct = 0; ct < 4; ++ct) {
      bf16x8 bh0 = *(const bf16x8*)(sB[cb] + (ct * 16 + m) * 32 + q * 8);
      bf16x8 bl0 = *(const bf16x8*)(sB[cb] + 2048 + (ct * 16 + m) * 32 + q * 8);
      acc[cb][ct] = __builtin_amdgcn_mfma_f32_16x16x32_bf16(ah0, bh0, acc[cb][ct], 0, 0, 0);
      acc[cb][ct] = __builtin_amdgcn_mfma_f32_16x16x32_bf16(ah0, bl0, acc[cb][ct], 0, 0, 0);
      acc[cb][ct] = __builtin_amdgcn_mfma_f32_16x16x32_bf16(al0, bh0, acc[cb][ct], 0, 0, 0);
      bf16x8 bh1 = *(const bf16x8*)(sB[cb] + 4096 + (ct * 16 + m) * 32 + q * 8);
      bf16x8 bl1 = *(const bf16x8*)(sB[cb] + 4096 + 2048 + (ct * 16 + m) * 32 + q * 8);
      acc[cb][ct] = __builtin_amdgcn_mfma_f32_16x16x32_bf16(ah1, bh1, acc[cb][ct], 0, 0, 0);
      acc[cb][ct] = __builtin_amdgcn_mfma_f32_16x16x32_bf16(ah1, bl1, acc[cb][ct], 0, 0, 0);
      acc[cb][ct] = __builtin_amdgcn_mfma_f32_16x16x32_bf16(al1, bh1, acc[cb][ct], 0, 0, 0);
    }
  }

  float g = 0.f, gi = 0.f;
  if (EPI_SKIP) { g = 1.0f / (1.0f + __expf(-skipPtr[0])); gi = 1.0f - g; }
#pragma unroll
  for (int cb = 0; cb < CB; ++cb) {
#pragma unroll
    for (int ct = 0; ct < 4; ++ct) {
      int c = cb * 64 + ct * 16 + m;
      float b = bias[c];
#pragma unroll
      for (int i = 0; i < 4; ++i) {
        int r = row0 + wv * 16 + q * 4 + i;
        if (r < nRows) {
          float o = acc[cb][ct][i] + b;
          if (EPI_SKIP) {
            float hp = Hprev[(size_t)r * 64 + c];
            o = fmaxf(g * o + gi * hp, 0.f);
          }
          outp[(size_t)r * ldOut + c] = o;
        }
      }
    }
  }
}

// ---------------- weight transpose + bf16 split into chunked layout ----------
// W[k][c] (row-major, ld=C) -> Wt chunk layout (see mfma_gemm header comment)
__global__ void prep_weights(const float* __restrict__ W, int K, int C,
                             ushort* __restrict__ Wt)
{
  int idx = blockIdx.x * 256 + threadIdx.x;
  if (idx < K * C) {
    int k = idx / C, c = idx % C;
    ushort h, l; split1(W[idx], h, l);
    int cb = c >> 6, cc = c & 63, ch = k >> 5, kk = k & 31;
    size_t base = (size_t)(cb * (K >> 5) + ch) * 4096;
    Wt[base + cc * 32 + kk] = h;
    Wt[base + 2048 + cc * 32 + kk] = l;
  }
}

// ---------------- fold a_rel / m_rel into packed qkv weights ------------------
// Wqkv[l]: [64][192]  col 0..63 = Wq; cols 64..191 = kt/vt INTERLEAVED:
//   kt_c -> 64 + 2c, vt_c -> 64 + 2c + 1  (so edge_agg reads one float2/lane)
__global__ void fold_weights(const float* __restrict__ Wq, const float* __restrict__ bq,
                             const float* __restrict__ Wk, const float* __restrict__ bk,
                             const float* __restrict__ Wv, const float* __restrict__ bv,
                             const float* __restrict__ a_rel, const float* __restrict__ m_rel,
                             float* __restrict__ Wqkv, float* __restrict__ bqkv)
{
  int l = blockIdx.x;
  const float* wq = Wq + l * 4096; const float* wk = Wk + l * 4096; const float* wv = Wv + l * 4096;
  const float* bql = bq + l * 64;  const float* bkl = bk + l * 64;  const float* bvl = bv + l * 64;
  const float* ar = a_rel + l * 1024; const float* mr = m_rel + l * 1024;
  float* W = Wqkv + l * 64 * 192;  float* B = bqkv + l * 192;
  for (int t = threadIdx.x; t < 64 * 192; t += blockDim.x) {
    int i = t / 192, c = t % 192;
    float val;
    int cp;  // permuted output column
    if (c < 64) {
      val = wq[i * 64 + c];
      cp = c;
    } else if (c < 128) {
      int cc = c - 64, hh = cc >> 4, f = cc & 15;
      float s = 0.f;
      for (int d = 0; d < 16; ++d) s += wk[i * 64 + hh * 16 + d] * ar[hh * 256 + d * 16 + f];
      val = s;
      cp = 64 + (cc << 1);
    } else {
      int cc = c - 128, hh = cc >> 4, f = cc & 15;
      float s = 0.f;
      for (int d = 0; d < 16; ++d) s += wv[i * 64 + hh * 16 + d] * mr[hh * 256 + d * 16 + f];
      val = s;
      cp = 64 + (cc << 1) + 1;
    }
    W[i * 192 + cp] = val;
  }
  for (int c = threadIdx.x; c < 192; c += blockDim.x) {
    float val;
    int cp;
    if (c < 64) {
      val = bql[c];
      cp = c;
    } else if (c < 128) {
      int cc = c - 64, hh = cc >> 4, f = cc & 15;
      float s = 0.f;
      for (int d = 0; d < 16; ++d) s += bkl[hh * 16 + d] * ar[hh * 256 + d * 16 + f];
      val = s;
      cp = 64 + (cc << 1);
    } else {
      int cc = c - 128, hh = cc >> 4, f = cc & 15;
      float s = 0.f;
      for (int d = 0; d < 16; ++d) s += bvl[hh * 16 + d] * mr[hh * 256 + d * 16 + f];
      val = s;
      cp = 64 + (cc << 1) + 1;
    }
    B[cp] = val;
  }
}

// ---------------- CSR construction -------------------------------------------
__global__ void hist_kernel(const int* __restrict__ dst, int* __restrict__ counts, int E) {
  int e = blockIdx.x * 256 + threadIdx.x;
  if (e < E) atomicAdd(&counts[dst[e]], 1);
}

__global__ __launch_bounds__(256)
void scanA(int* __restrict__ counts, int* __restrict__ blockSums, int n) {
  __shared__ int sd[256];
  int tid = threadIdx.x;
  int base = blockIdx.x * 1024 + tid * 4;
  int v[4];
#pragma unroll
  for (int j = 0; j < 4; ++j) v[j] = (base + j < n) ? counts[base + j] : 0;
  int t = v[0] + v[1] + v[2] + v[3];
  sd[tid] = t; __syncthreads();
  for (int offm = 1; offm < 256; offm <<= 1) {
    int adj = (tid >= offm) ? sd[tid - offm] : 0;
    __syncthreads();
    sd[tid] += adj;
    __syncthreads();
  }
  int run = sd[tid] - t;  // exclusive prefix for this thread
#pragma unroll
  for (int j = 0; j < 4; ++j) {
    if (base + j < n) counts[base + j] = run;
    run += v[j];
  }
  if (tid == 255) blockSums[blockIdx.x] = sd[255];
}

__global__ void scanB(int* __restrict__ blockSums, int G, int* __restrict__ row_ptr, int n) {
  __shared__ int sd[128];
  int tid = threadIdx.x;
  int t = (tid < G) ? blockSums[tid] : 0;
  sd[tid] = t; __syncthreads();
  for (int offm = 1; offm < 128; offm <<= 1) {
    int adj = (tid >= offm) ? sd[tid - offm] : 0;
    __syncthreads();
    sd[tid] += adj;
    __syncthreads();
  }
  if (tid < G) blockSums[tid] = sd[tid] - t;
  if (tid == 127) row_ptr[n] = sd[127];  // total = E
}

__global__ void scanC(const int* __restrict__ counts, const int* __restrict__ blockSums,
                      int* __restrict__ row_ptr, int* __restrict__ cursor, int n) {
  int idx = blockIdx.x * 256 + threadIdx.x;
  if (idx < n) {
    int v = counts[idx] + blockSums[idx >> 10];
    row_ptr[idx] = v;
    cursor[idx] = v;
  }
}

__global__ void scatter_kernel(const int* __restrict__ src, const int* __restrict__ dst,
                               int* __restrict__ cursor, int* __restrict__ csr_src, int E) {
  int e = blockIdx.x * 256 + threadIdx.x;
  if (e < E) {
    int d = dst[e];
    int pos = atomicAdd(&cursor[d], 1);
    csr_src[pos] = src[e];
  }
}

// ---------------- fused attention aggregation: one wave per dst node ----------
// lane = head*16 + f. qkv row layout: [q(64) | ktvt interleaved(128)], ld=192.
// 8-wide masked edge unroll; CSR indices scalarized (s_load + scalar gather
// bases); 16-lane dot reduce via DPP rotation (red16), not DS-pipe shuffles.
__global__ __launch_bounds__(256)
void edge_agg(const float* __restrict__ qkv, const int* __restrict__ row_ptr,
              const int* __restrict__ csr_src, const float* __restrict__ p_rel,
              float* __restrict__ agg, int n)
{
  int wid = blockIdx.x * 4 + (threadIdx.x >> 6);
  if (wid >= n) return;
  int lane = threadIdx.x & 63;
  int head = lane >> 4;
  float pr = p_rel[head] * 0.25f;  // p_rel / sqrt(D), D=16
  float qv = qkv[(size_t)wid * 192 + lane] * pr;  // prescaled
  int e0 = __builtin_amdgcn_readfirstlane(row_ptr[wid]);
  int e1 = __builtin_amdgcn_readfirstlane(row_ptr[wid + 1]);
  const float* ktb = qkv + 64 + 2 * lane;  // scalar row base + per-lane offset
  float num = 0.f, den = 0.f;
  for (int e = e0; e < e1; e += 8) {
    int last = e1 - 1;
    int i1 = (e + 1 < e1) ? e + 1 : last;
    int i2 = (e + 2 < e1) ? e + 2 : last;
    int i3 = (e + 3 < e1) ? e + 3 : last;
    int i4 = (e + 4 < e1) ? e + 4 : last;
    int i5 = (e + 5 < e1) ? e + 5 : last;
    int i6 = (e + 6 < e1) ? e + 6 : last;
    int i7 = (e + 7 < e1) ? e + 7 : last;
    int s0 = __builtin_amdgcn_readfirstlane(csr_src[e]);
    int s1 = __builtin_amdgcn_readfirstlane(csr_src[i1]);
    int s2 = __builtin_amdgcn_readfirstlane(csr_src[i2]);
    int s3 = __builtin_amdgcn_readfirstlane(csr_src[i3]);
    int s4 = __builtin_amdgcn_readfirstlane(csr_src[i4]);
    int s5 = __builtin_amdgcn_readfirstlane(csr_src[i5]);
    int s6 = __builtin_amdgcn_readfirstlane(csr_src[i6]);
    int s7 = __builtin_amdgcn_readfirstlane(csr_src[i7]);
    float2 kv0 = *(const float2*)(ktb + (size_t)s0 * 192);
    float2 kv1 = *(const float2*)(ktb + (size_t)s1 * 192);
    float2 kv2 = *(const float2*)(ktb + (size_t)s2 * 192);
    float2 kv3 = *(const float2*)(ktb + (size_t)s3 * 192);
    float2 kv4 = *(const float2*)(ktb + (size_t)s4 * 192);
    float2 kv5 = *(const float2*)(ktb + (size_t)s5 * 192);
    float2 kv6 = *(const float2*)(ktb + (size_t)s6 * 192);
    float2 kv7 = *(const float2*)(ktb + (size_t)s7 * 192);
    float p0 = red16(kv0.x * qv);
    float p1 = red16(kv1.x * qv);
    float p2 = red16(kv2.x * qv);
    float p3 = red16(kv3.x * qv);
    float p4 = red16(kv4.x * qv);
    float p5 = red16(kv5.x * qv);
    float p6 = red16(kv6.x * qv);
    float p7 = red16(kv7.x * qv);
    float w0 = __expf(p0);
    float w1 = (e + 1 < e1) ? __expf(p1) : 0.f;
    float w2 = (e + 2 < e1) ? __expf(p2) : 0.f;
    float w3 = (e + 3 < e1) ? __expf(p3) : 0.f;
    float w4 = (e + 4 < e1) ? __expf(p4) : 0.f;
    float w5 = (e + 5 < e1) ? __expf(p5) : 0.f;
    float w6 = (e + 6 < e1) ? __expf(p6) : 0.f;
    float w7 = (e + 7 < e1) ? __expf(p7) : 0.f;
    den += ((w0 + w1) + (w2 + w3)) + ((w4 + w5) + (w6 + w7));
    num = fmaf(w0, kv0.y, num);
    num = fmaf(w1, kv1.y, num);
    num = fmaf(w2, kv2.y, num);
    num = fmaf(w3, kv3.y, num);
    num = fmaf(w4, kv4.y, num);
    num = fmaf(w5, kv5.y, num);
    num = fmaf(w6, kv6.y, num);
    num = fmaf(w7, kv7.y, num);
  }
  agg[(size_t)wid * 64 + lane] = num / (den + 1e-16f);
}

// ---------------- classifier: 64 -> relu(32) -> 2 ----------------------------
__global__ __launch_bounds__(256)
void classifier(const float* __restrict__ h, const float* __restrict__ Wc1,
                const float* __restrict__ bc1, const float* __restrict__ Wc2,
                const float* __restrict__ bc2, float* __restrict__ out, int n)
{
  int row = blockIdx.x * 256 + threadIdx.x;
  if (row >= n) return;
  float hid[32];
#pragma unroll
  for (int j = 0; j < 32; ++j) hid[j] = bc1[j];
  const float* hr = h + (size_t)row * 64;
#pragma unroll 4
  for (int k = 0; k < 64; k += 4) {
    float4 x = *(const float4*)&hr[k];
#pragma unroll
    for (int j = 0; j < 32; ++j) {
      hid[j] += x.x * Wc1[k * 32 + j] + x.y * Wc1[(k + 1) * 32 + j]
              + x.z * Wc1[(k + 2) * 32 + j] + x.w * Wc1[(k + 3) * 32 + j];
    }
  }
  float o0 = bc2[0], o1 = bc2[1];
#pragma unroll
  for (int j = 0; j < 32; ++j) {
    float v = fmaxf(hid[j], 0.f);
    o0 += v * Wc2[j * 2 + 0];
    o1 += v * Wc2[j * 2 + 1];
  }
  *(float2*)&out[(size_t)row * 2] = make_float2(o0, o1);
}

// ---------------------------------------------------------------------------
extern "C" void kernel_launch(void* const* d_in, const int* in_sizes, int n_in,
                              void* d_out, int out_size, void* d_ws, size_t ws_size,
                              hipStream_t stream)
{
  const float* x     = (const float*)d_in[0];
  const int*  eidx   = (const int*)d_in[1];
  const float* Wp    = (const float*)d_in[2];
  const float* bp    = (const float*)d_in[3];
  const float* Wk    = (const float*)d_in[4];
  const float* bk    = (const float*)d_in[5];
  const float* Wq    = (const float*)d_in[6];
  const float* bq    = (const float*)d_in[7];
  const float* Wv    = (const float*)d_in[8];
  const float* bv    = (const float*)d_in[9];
  const float* a_rel = (const float*)d_in[10];
  const float* m_rel = (const float*)d_in[11];
  const float* p_rel = (const float*)d_in[12];
  const float* Wo    = (const float*)d_in[13];
  const float* bo    = (const float*)d_in[14];
  const float* skip  = (const float*)d_in[15];
  const float* Wc1   = (const float*)d_in[16];
  const float* bc1   = (const float*)d_in[17];
  const float* Wc2   = (const float*)d_in[18];
  const float* bc2   = (const float*)d_in[19];
  float* out = (float*)d_out;

  const int N = in_sizes[0] / 768;
  const int E = in_sizes[1] / 2;
  const int* srcIdx = eidx;
  const int* dstIdx = eidx + E;

  char* ws = (char*)d_ws;
  size_t off = 0;
  auto alloc = [&](size_t bytes) -> void* {
    void* p = ws + off;
    off = (off + bytes + 255) & ~(size_t)255;
    return p;
  };
  float* h     = (float*)alloc((size_t)N * 64 * 4);
  float* qkv   = (float*)alloc((size_t)N * 192 * 4);
  float* agg   = (float*)alloc((size_t)N * 64 * 4);
  float* Wqkv  = (float*)alloc(2 * 64 * 192 * 4);
  float* bqkv  = (float*)alloc(2 * 192 * 4);
  int* row_ptr = (int*)alloc((size_t)(N + 1) * 4);
  int* cursor  = (int*)alloc((size_t)N * 4);
  int* counts  = (int*)alloc((size_t)N * 4);
  int* blockSums = (int*)alloc(512 * 4);
  int* csr_src = (int*)alloc((size_t)E * 4);
  // split-bf16 chunked weights (h+l interleaved per 64x32 chunk)
  ushort* WtP   = (ushort*)alloc((size_t)64 * 768 * 2 * 2);
  ushort* WtQKV = (ushort*)alloc((size_t)2 * 192 * 64 * 2 * 2);
  ushort* WtO   = (ushort*)alloc((size_t)2 * 64 * 64 * 2 * 2);
  (void)ws_size; (void)n_in; (void)out_size;

  hipMemsetAsync(counts, 0, (size_t)N * 4, stream);

  fold_weights<<<2, 256, 0, stream>>>(Wq, bq, Wk, bk, Wv, bv, a_rel, m_rel, Wqkv, bqkv);

  // transpose + split all GEMM weights into chunked layout (tiny, once)
  prep_weights<<<(768 * 64 + 255) / 256, 256, 0, stream>>>(Wp, 768, 64, WtP);
  for (int l = 0; l < 2; ++l) {
    prep_weights<<<(64 * 192 + 255) / 256, 256, 0, stream>>>(
        Wqkv + l * 64 * 192, 64, 192, WtQKV + (size_t)l * 192 * 64 * 2);
    prep_weights<<<(64 * 64 + 255) / 256, 256, 0, stream>>>(
        Wo + l * 4096, 64, 64, WtO + (size_t)l * 64 * 64 * 2);
  }

  // input projection: h = x @ Wp + bp
  mfma_gemm<768, false, false><<<dim3((N + 63) / 64, 1), 256, 0, stream>>>(
      x, 768, WtP, bp, nullptr, nullptr, h, 64, N);

  // CSR build (shared by both layers)
  hist_kernel<<<(E + 255) / 256, 256, 0, stream>>>(dstIdx, counts, E);
  int G = (N + 1023) / 1024;
  scanA<<<G, 256, 0, stream>>>(counts, blockSums, N);
  scanB<<<1, 128, 0, stream>>>(blockSums, G, row_ptr, N);
  scanC<<<(N + 255) / 256, 256, 0, stream>>>(counts, blockSums, row_ptr, cursor, N);
  scatter_kernel<<<(E + 255) / 256, 256, 0, stream>>>(srcIdx, dstIdx, cursor, csr_src, E);

  for (int l = 0; l < 2; ++l) {
    // fused q | ktvt projection: [N,64] @ [64,192], A read ONCE (CB=3)
    mfma_gemm_k64<3, false, false><<<(N + 63) / 64, 256, 0, stream>>>(
        h, WtQKV + (size_t)l * 192 * 64 * 2, bqkv + l * 192,
        nullptr, nullptr, qkv, 192, N);
    // attention + aggregation
    edge_agg<<<(N + 3) / 4, 256, 0, stream>>>(qkv, row_ptr, csr_src, p_rel + l * 4, agg, N);
    // out = relu(g*(gelu(agg)@Wo + bo) + (1-g)*h), in-place into h
    mfma_gemm_k64<1, true, true><<<(N + 63) / 64, 256, 0, stream>>>(
        agg, WtO + (size_t)l * 64 * 64 * 2, bo + l * 64, h, skip + l, h, 64, N);
  }

  classifier<<<(N + 255) / 256, 256, 0, stream>>>(h, Wc1, bc1, Wc2, bc2, out, N);
}

// Round 4
// 937.870 us; speedup vs baseline: 1.1415x; 1.1415x over previous
//
#include <hip/hip_runtime.h>
#include <hip/hip_fp16.h>
#include <math.h>

// ---------------------------------------------------------------------------
// SimpleLESS4FDModel: 2-layer HGT on a homogeneous graph.
// a_rel / m_rel folded into projection weights (fold_weights).
// Per edge:  alpha = <kt[src], q[dst]>_head * p_rel / 4 ;
//   agg[dst] = sum_e exp(alpha) * vt[src] / (sum_e exp(alpha) + 1e-16)
// CSR (built once, reused by both layers) makes aggregation atomic-free.
//
// R3: split-bf16 MFMA GEMM (ah*bh+ah*bl+al*bh).  R4: LDS-staged K-loop.
// R5: kt/vt interleave + 4-wide edge unroll (1053us).
// R6/R7: 8-wide + readfirstlane + DPP + flat k64 GEMM (1070us, ~neutral:
//   edge_agg is gather-THROUGHPUT-bound, extra MLP stopped paying; masked
//   duplicate gathers are L1 hits, not BW).
// R8 (this): halve gather bytes -- kt/vt packed fp16 (half2(kt,vt) per
//   channel = ONE dword per lane per edge). Pack is free in the qkv GEMM
//   epilogue via plane layout kt->64+c, vt->128+c (same lane holds both).
//   qkv row: [q fp32 x64 | half2 x64] = 512B. Drop explicit readfirstlane on
//   csr_src (R1-style plain loads measured best); keep DPP red16 (pure VALU);
//   out-proj k64 GEMM occupancy 2->4 blocks/CU (32KB LDS).
// ---------------------------------------------------------------------------

typedef __attribute__((ext_vector_type(8))) short bf16x8;  // 8 bf16 (4 VGPRs)
typedef __attribute__((ext_vector_type(4))) float f32x4;

__device__ __forceinline__ float gelu_t(float x) {
  const float c = 0.7978845608028654f;  // sqrt(2/pi)
  float t = tanhf(c * (x + 0.044715f * x * x * x));
  return 0.5f * x * (1.0f + t);
}

// split fp32 -> bf16 hi (truncate) + bf16 lo (truncate of remainder)
__device__ __forceinline__ void split1(float a, ushort& h, ushort& l) {
  unsigned u = __float_as_uint(a);
  unsigned uh = u & 0xffff0000u;
  float fl = a - __uint_as_float(uh);
  h = (ushort)(uh >> 16);
  l = (ushort)(__float_as_uint(fl) >> 16);
}

// 16-lane rotation-reduce via DPP row_ror (rotations 1,2,4,8 span the cyclic
// group -> every lane ends with the full 16-lane sum). Pure VALU, no DS pipe.
template<int CTRL>
__device__ __forceinline__ float row_ror_add(float v) {
  int r = __builtin_amdgcn_update_dpp(0, __float_as_int(v), CTRL, 0xF, 0xF, true);
  return v + __int_as_float(r);
}
__device__ __forceinline__ float red16(float v) {
  v = row_ror_add<0x121>(v);  // ror 1
  v = row_ror_add<0x122>(v);  // ror 2
  v = row_ror_add<0x124>(v);  // ror 4
  v = row_ror_add<0x128>(v);  // ror 8
  return v;
}

// ---------------- split-bf16 MFMA GEMM, LDS-staged (K=768 streaming) ---------
// out[r, colBlk+c] = A[r,:] @ W[:,c] + bias[c]
// Block: 256 threads = 4 waves; 64 rows x 64 cols per block.
// Wt layout (ushort): per colBlk cb, per 32-k chunk ch: 4096 ushorts =
//   [h: c(64) x k(32)] ++ [l: c(64) x k(32)]   (contiguous 8 KB per chunk)
template<int K>
__global__ __launch_bounds__(256, 4)
void mfma_gemm(const float* __restrict__ A, int ldA,
               const ushort* __restrict__ Wt,
               const float* __restrict__ bias,
               float* __restrict__ outp, int ldOut, int nRows)
{
  constexpr int NCH = K / 32;
  __shared__ ushort sA[2 * 64 * 32];  // h at 0, l at +2048 (8 KB)
  __shared__ ushort sB[2 * 64 * 32];  // h at 0, l at +2048 (8 KB)
  const int tid = threadIdx.x;
  const int lane = tid & 63;
  const int wv = tid >> 6;
  const int m = lane & 15;   // A row / B col / C col within tile
  const int q = lane >> 4;   // quad
  const int row0 = blockIdx.x * 64;
  const int colBlk = blockIdx.y * 64;

  // staging roles: thread t stages A row (t>>2), k-offset (t&3)*8 (32 B)
  const int srow = tid >> 2;
  const int skoff = (tid & 3) * 8;
  int gr = row0 + srow; if (gr >= nRows) gr = nRows - 1;  // clamp; masked at store
  const float* aBase = A + (size_t)gr * ldA + skoff;
  const float4* wBase = (const float4*)(Wt + (size_t)blockIdx.y * NCH * 4096);

  f32x4 acc[4];
#pragma unroll
  for (int ct = 0; ct < 4; ++ct) acc[ct] = (f32x4){0.f, 0.f, 0.f, 0.f};

  // prefetch chunk 0 into registers
  float4 a0 = *(const float4*)(aBase + 0);
  float4 a1 = *(const float4*)(aBase + 4);
  float4 b0 = wBase[tid * 2];
  float4 b1 = wBase[tid * 2 + 1];

#pragma clang loop unroll(disable)
  for (int ch = 0; ch < NCH; ++ch) {
    float4 na0 = a0, na1 = a1, nb0 = b0, nb1 = b1;
    if (ch + 1 < NCH) {  // issue next chunk's global loads before consuming cur
      na0 = *(const float4*)(aBase + (ch + 1) * 32);
      na1 = *(const float4*)(aBase + (ch + 1) * 32 + 4);
      const float4* wc = wBase + (size_t)(ch + 1) * 512;  // 4096 ushorts = 512 float4
      nb0 = wc[tid * 2];
      nb1 = wc[tid * 2 + 1];
    }
    float av[8] = {a0.x, a0.y, a0.z, a0.w, a1.x, a1.y, a1.z, a1.w};
    bf16x8 vh, vl;
#pragma unroll
    for (int j = 0; j < 8; ++j) {
      ushort h, l; split1(av[j], h, l);
      vh[j] = (short)h; vl[j] = (short)l;
    }
    __syncthreads();  // previous chunk's LDS reads complete before overwrite
    *(bf16x8*)(sA + srow * 32 + skoff) = vh;
    *(bf16x8*)(sA + 2048 + srow * 32 + skoff) = vl;
    ((float4*)sB)[tid * 2] = b0;
    ((float4*)sB)[tid * 2 + 1] = b1;
    __syncthreads();
    bf16x8 ah = *(const bf16x8*)(sA + (wv * 16 + m) * 32 + q * 8);
    bf16x8 al = *(const bf16x8*)(sA + 2048 + (wv * 16 + m) * 32 + q * 8);
#pragma unroll
    for (int ct = 0; ct < 4; ++ct) {
      bf16x8 bh = *(const bf16x8*)(sB + (ct * 16 + m) * 32 + q * 8);
      bf16x8 bl = *(const bf16x8*)(sB + 2048 + (ct * 16 + m) * 32 + q * 8);
      acc[ct] = __builtin_amdgcn_mfma_f32_16x16x32_bf16(ah, bh, acc[ct], 0, 0, 0);
      acc[ct] = __builtin_amdgcn_mfma_f32_16x16x32_bf16(ah, bl, acc[ct], 0, 0, 0);
      acc[ct] = __builtin_amdgcn_mfma_f32_16x16x32_bf16(al, bh, acc[ct], 0, 0, 0);
    }
    a0 = na0; a1 = na1; b0 = nb0; b1 = nb1;
  }

  // epilogue: C/D layout col = lane&15 (=m), row = quad*4 + reg  [m89-verified]
#pragma unroll
  for (int ct = 0; ct < 4; ++ct) {
    int c = colBlk + ct * 16 + m;
    float b = bias[c];
#pragma unroll
    for (int i = 0; i < 4; ++i) {
      int r = row0 + wv * 16 + q * 4 + i;
      if (r < nRows) outp[(size_t)r * ldOut + c] = acc[ct][i] + b;
    }
  }
}

// ---------------- flat K=64 GEMM: whole problem staged once, ONE barrier -----
// A is [nRows,64] fp32. Wt holds CB col-blocks in the chunked layout.
// EPI: 0 = plain(+bias), 1 = gelu(A) + skip epilogue, 2 = qkv pack
//   (CB==3: plane0 = q fp32 -> out[r*128+c]; plane1=kt, plane2=vt ->
//    half2(kt,vt) at dword 64+c; out row = 128 dwords).
template<int CB, int EPI>
__global__ __launch_bounds__(256, (CB == 1) ? 4 : 2)
void mfma_gemm_k64(const float* __restrict__ A,
                   const ushort* __restrict__ Wt,
                   const float* __restrict__ bias,
                   const float* __restrict__ Hprev,
                   const float* __restrict__ skipPtr,
                   float* __restrict__ outp, int ldOut, int nRows)
{
  __shared__ ushort sA[2 * 4096];        // [ch][h(2048) ++ l(2048)]
  __shared__ ushort sB[CB][2 * 4096];
  const int tid = threadIdx.x;
  const int lane = tid & 63;
  const int wv = tid >> 6;
  const int m = lane & 15;
  const int q = lane >> 4;
  const int row0 = blockIdx.x * 64;
  const int srow = tid >> 2;
  const int skoff = (tid & 3) * 8;
  int gr = row0 + srow; if (gr >= nRows) gr = nRows - 1;
  const float* aBase = A + (size_t)gr * 64 + skoff;
  const float4* wBase = (const float4*)Wt;

  // issue ALL global loads up front
  float4 a0 = *(const float4*)(aBase + 0);
  float4 a1 = *(const float4*)(aBase + 4);
  float4 a2 = *(const float4*)(aBase + 32);
  float4 a3 = *(const float4*)(aBase + 36);
  float4 bb0[CB], bb1[CB], bb2[CB], bb3[CB];
#pragma unroll
  for (int cb = 0; cb < CB; ++cb) {
    bb0[cb] = wBase[(size_t)(cb * 2 + 0) * 512 + tid * 2];
    bb1[cb] = wBase[(size_t)(cb * 2 + 0) * 512 + tid * 2 + 1];
    bb2[cb] = wBase[(size_t)(cb * 2 + 1) * 512 + tid * 2];
    bb3[cb] = wBase[(size_t)(cb * 2 + 1) * 512 + tid * 2 + 1];
  }

  // split + store A (both 32-k chunks)
  {
    float av[16] = {a0.x, a0.y, a0.z, a0.w, a1.x, a1.y, a1.z, a1.w,
                    a2.x, a2.y, a2.z, a2.w, a3.x, a3.y, a3.z, a3.w};
    if (EPI == 1) {
#pragma unroll
      for (int j = 0; j < 16; ++j) av[j] = gelu_t(av[j]);
    }
    bf16x8 vh0, vl0, vh1, vl1;
#pragma unroll
    for (int j = 0; j < 8; ++j) {
      ushort h, l; split1(av[j], h, l);
      vh0[j] = (short)h; vl0[j] = (short)l;
    }
#pragma unroll
    for (int j = 0; j < 8; ++j) {
      ushort h, l; split1(av[8 + j], h, l);
      vh1[j] = (short)h; vl1[j] = (short)l;
    }
    *(bf16x8*)(sA + srow * 32 + skoff) = vh0;
    *(bf16x8*)(sA + 2048 + srow * 32 + skoff) = vl0;
    *(bf16x8*)(sA + 4096 + srow * 32 + skoff) = vh1;
    *(bf16x8*)(sA + 4096 + 2048 + srow * 32 + skoff) = vl1;
  }
#pragma unroll
  for (int cb = 0; cb < CB; ++cb) {
    ((float4*)(sB[cb]))[tid * 2] = bb0[cb];
    ((float4*)(sB[cb]))[tid * 2 + 1] = bb1[cb];
    ((float4*)(sB[cb] + 4096))[tid * 2] = bb2[cb];
    ((float4*)(sB[cb] + 4096))[tid * 2 + 1] = bb3[cb];
  }
  __syncthreads();

  f32x4 acc[CB][4];
#pragma unroll
  for (int cb = 0; cb < CB; ++cb)
#pragma unroll
    for (int ct = 0; ct < 4; ++ct) acc[cb][ct] = (f32x4){0.f, 0.f, 0.f, 0.f};

  bf16x8 ah0 = *(const bf16x8*)(sA + (wv * 16 + m) * 32 + q * 8);
  bf16x8 al0 = *(const bf16x8*)(sA + 2048 + (wv * 16 + m) * 32 + q * 8);
  bf16x8 ah1 = *(const bf16x8*)(sA + 4096 + (wv * 16 + m) * 32 + q * 8);
  bf16x8 al1 = *(const bf16x8*)(sA + 4096 + 2048 + (wv * 16 + m) * 32 + q * 8);
#pragma unroll
  for (int cb = 0; cb < CB; ++cb) {
#pragma unroll
    for (int ct = 0; ct < 4; ++ct) {
      bf16x8 bh0 = *(const bf16x8*)(sB[cb] + (ct * 16 + m) * 32 + q * 8);
      bf16x8 bl0 = *(const bf16x8*)(sB[cb] + 2048 + (ct * 16 + m) * 32 + q * 8);
      acc[cb][ct] = __builtin_amdgcn_mfma_f32_16x16x32_bf16(ah0, bh0, acc[cb][ct], 0, 0, 0);
      acc[cb][ct] = __builtin_amdgcn_mfma_f32_16x16x32_bf16(ah0, bl0, acc[cb][ct], 0, 0, 0);
      acc[cb][ct] = __builtin_amdgcn_mfma_f32_16x16x32_bf16(al0, bh0, acc[cb][ct], 0, 0, 0);
      bf16x8 bh1 = *(const bf16x8*)(sB[cb] + 4096 + (ct * 16 + m) * 32 + q * 8);
      bf16x8 bl1 = *(const bf16x8*)(sB[cb] + 4096 + 2048 + (ct * 16 + m) * 32 + q * 8);
      acc[cb][ct] = __builtin_amdgcn_mfma_f32_16x16x32_bf16(ah1, bh1, acc[cb][ct], 0, 0, 0);
      acc[cb][ct] = __builtin_amdgcn_mfma_f32_16x16x32_bf16(ah1, bl1, acc[cb][ct], 0, 0, 0);
      acc[cb][ct] = __builtin_amdgcn_mfma_f32_16x16x32_bf16(al1, bh1, acc[cb][ct], 0, 0, 0);
    }
  }

  if (EPI == 2) {
    // q plane fp32 + packed half2(kt, vt); out row = 128 dwords
#pragma unroll
    for (int ct = 0; ct < 4; ++ct) {
      int c = ct * 16 + m;
      float bq_ = bias[c], bk_ = bias[64 + c], bv_ = bias[128 + c];
#pragma unroll
      for (int i = 0; i < 4; ++i) {
        int r = row0 + wv * 16 + q * 4 + i;
        if (r < nRows) {
          outp[(size_t)r * 128 + c] = acc[0][ct][i] + bq_;
          __half2 kv = __floats2half2_rn(acc[1][ct][i] + bk_, acc[2][ct][i] + bv_);
          *((__half2*)outp + (size_t)r * 128 + 64 + c) = kv;
        }
      }
    }
  } else {
    float g = 0.f, gi = 0.f;
    if (EPI == 1) { g = 1.0f / (1.0f + __expf(-skipPtr[0])); gi = 1.0f - g; }
#pragma unroll
    for (int cb = 0; cb < CB; ++cb) {
#pragma unroll
      for (int ct = 0; ct < 4; ++ct) {
        int c = cb * 64 + ct * 16 + m;
        float b = bias[c];
#pragma unroll
        for (int i = 0; i < 4; ++i) {
          int r = row0 + wv * 16 + q * 4 + i;
          if (r < nRows) {
            float o = acc[cb][ct][i] + b;
            if (EPI == 1) {
              float hp = Hprev[(size_t)r * 64 + c];
              o = fmaxf(g * o + gi * hp, 0.f);
            }
            outp[(size_t)r * ldOut + c] = o;
          }
        }
      }
    }
  }
}

// ---------------- weight transpose + bf16 split into chunked layout ----------
__global__ void prep_weights(const float* __restrict__ W, int K, int C,
                             ushort* __restrict__ Wt)
{
  int idx = blockIdx.x * 256 + threadIdx.x;
  if (idx < K * C) {
    int k = idx / C, c = idx % C;
    ushort h, l; split1(W[idx], h, l);
    int cb = c >> 6, cc = c & 63, ch = k >> 5, kk = k & 31;
    size_t base = (size_t)(cb * (K >> 5) + ch) * 4096;
    Wt[base + cc * 32 + kk] = h;
    Wt[base + 2048 + cc * 32 + kk] = l;
  }
}

// ---------------- fold a_rel / m_rel into packed qkv weights ------------------
// Wqkv[l]: [64][192]  cols 0..63 = Wq, 64..127 = Wk@a_rel (kt), 128..191 =
// Wv@m_rel (vt)  -- plane layout so the GEMM pack epilogue has kt_c and vt_c
// in the same lane (acc[1] / acc[2], same (ct,m,i)).
__global__ void fold_weights(const float* __restrict__ Wq, const float* __restrict__ bq,
                             const float* __restrict__ Wk, const float* __restrict__ bk,
                             const float* __restrict__ Wv, const float* __restrict__ bv,
                             const float* __restrict__ a_rel, const float* __restrict__ m_rel,
                             float* __restrict__ Wqkv, float* __restrict__ bqkv)
{
  int l = blockIdx.x;
  const float* wq = Wq + l * 4096; const float* wk = Wk + l * 4096; const float* wv = Wv + l * 4096;
  const float* bql = bq + l * 64;  const float* bkl = bk + l * 64;  const float* bvl = bv + l * 64;
  const float* ar = a_rel + l * 1024; const float* mr = m_rel + l * 1024;
  float* W = Wqkv + l * 64 * 192;  float* B = bqkv + l * 192;
  for (int t = threadIdx.x; t < 64 * 192; t += blockDim.x) {
    int i = t / 192, c = t % 192;
    float val;
    if (c < 64) {
      val = wq[i * 64 + c];
    } else if (c < 128) {
      int cc = c - 64, hh = cc >> 4, f = cc & 15;
      float s = 0.f;
      for (int d = 0; d < 16; ++d) s += wk[i * 64 + hh * 16 + d] * ar[hh * 256 + d * 16 + f];
      val = s;
    } else {
      int cc = c - 128, hh = cc >> 4, f = cc & 15;
      float s = 0.f;
      for (int d = 0; d < 16; ++d) s += wv[i * 64 + hh * 16 + d] * mr[hh * 256 + d * 16 + f];
      val = s;
    }
    W[i * 192 + c] = val;
  }
  for (int c = threadIdx.x; c < 192; c += blockDim.x) {
    float val;
    if (c < 64) {
      val = bql[c];
    } else if (c < 128) {
      int cc = c - 64, hh = cc >> 4, f = cc & 15;
      float s = 0.f;
      for (int d = 0; d < 16; ++d) s += bkl[hh * 16 + d] * ar[hh * 256 + d * 16 + f];
      val = s;
    } else {
      int cc = c - 128, hh = cc >> 4, f = cc & 15;
      float s = 0.f;
      for (int d = 0; d < 16; ++d) s += bvl[hh * 16 + d] * mr[hh * 256 + d * 16 + f];
      val = s;
    }
    B[c] = val;
  }
}

// ---------------- CSR construction -------------------------------------------
__global__ void hist_kernel(const int* __restrict__ dst, int* __restrict__ counts, int E) {
  int e = blockIdx.x * 256 + threadIdx.x;
  if (e < E) atomicAdd(&counts[dst[e]], 1);
}

__global__ __launch_bounds__(256)
void scanA(int* __restrict__ counts, int* __restrict__ blockSums, int n) {
  __shared__ int sd[256];
  int tid = threadIdx.x;
  int base = blockIdx.x * 1024 + tid * 4;
  int v[4];
#pragma unroll
  for (int j = 0; j < 4; ++j) v[j] = (base + j < n) ? counts[base + j] : 0;
  int t = v[0] + v[1] + v[2] + v[3];
  sd[tid] = t; __syncthreads();
  for (int offm = 1; offm < 256; offm <<= 1) {
    int adj = (tid >= offm) ? sd[tid - offm] : 0;
    __syncthreads();
    sd[tid] += adj;
    __syncthreads();
  }
  int run = sd[tid] - t;  // exclusive prefix for this thread
#pragma unroll
  for (int j = 0; j < 4; ++j) {
    if (base + j < n) counts[base + j] = run;
    run += v[j];
  }
  if (tid == 255) blockSums[blockIdx.x] = sd[255];
}

__global__ void scanB(int* __restrict__ blockSums, int G, int* __restrict__ row_ptr, int n) {
  __shared__ int sd[128];
  int tid = threadIdx.x;
  int t = (tid < G) ? blockSums[tid] : 0;
  sd[tid] = t; __syncthreads();
  for (int offm = 1; offm < 128; offm <<= 1) {
    int adj = (tid >= offm) ? sd[tid - offm] : 0;
    __syncthreads();
    sd[tid] += adj;
    __syncthreads();
  }
  if (tid < G) blockSums[tid] = sd[tid] - t;
  if (tid == 127) row_ptr[n] = sd[127];  // total = E
}

__global__ void scanC(const int* __restrict__ counts, const int* __restrict__ blockSums,
                      int* __restrict__ row_ptr, int* __restrict__ cursor, int n) {
  int idx = blockIdx.x * 256 + threadIdx.x;
  if (idx < n) {
    int v = counts[idx] + blockSums[idx >> 10];
    row_ptr[idx] = v;
    cursor[idx] = v;
  }
}

__global__ void scatter_kernel(const int* __restrict__ src, const int* __restrict__ dst,
                               int* __restrict__ cursor, int* __restrict__ csr_src, int E) {
  int e = blockIdx.x * 256 + threadIdx.x;
  if (e < E) {
    int d = dst[e];
    int pos = atomicAdd(&cursor[d], 1);
    csr_src[pos] = src[e];
  }
}

// ---------------- fused attention aggregation: one wave per dst node ----------
// lane = head*16 + f. qkv row: [q fp32 x64 | half2(kt,vt) x64], 128 dwords.
// 8-wide masked edge unroll (duplicate tail gathers are L1 hits); ONE dword
// gather per lane per edge; DPP rotation-reduce (VALU) for the 16-lane dot.
__global__ __launch_bounds__(256)
void edge_agg(const float* __restrict__ qkv, const int* __restrict__ row_ptr,
              const int* __restrict__ csr_src, const float* __restrict__ p_rel,
              float* __restrict__ agg, int n)
{
  int wid = blockIdx.x * 4 + (threadIdx.x >> 6);
  if (wid >= n) return;
  int lane = threadIdx.x & 63;
  int head = lane >> 4;
  float pr = p_rel[head] * 0.25f;  // p_rel / sqrt(D), D=16
  float qv = qkv[(size_t)wid * 128 + lane] * pr;  // prescaled
  int e0 = __builtin_amdgcn_readfirstlane(row_ptr[wid]);
  int e1 = __builtin_amdgcn_readfirstlane(row_ptr[wid + 1]);
  const __half2* ktb = (const __half2*)qkv + 64 + lane;
  float num = 0.f, den = 0.f;
  for (int e = e0; e < e1; e += 8) {
    int last = e1 - 1;
    int i1 = (e + 1 < e1) ? e + 1 : last;
    int i2 = (e + 2 < e1) ? e + 2 : last;
    int i3 = (e + 3 < e1) ? e + 3 : last;
    int i4 = (e + 4 < e1) ? e + 4 : last;
    int i5 = (e + 5 < e1) ? e + 5 : last;
    int i6 = (e + 6 < e1) ? e + 6 : last;
    int i7 = (e + 7 < e1) ? e + 7 : last;
    int s0 = csr_src[e];
    int s1 = csr_src[i1];
    int s2 = csr_src[i2];
    int s3 = csr_src[i3];
    int s4 = csr_src[i4];
    int s5 = csr_src[i5];
    int s6 = csr_src[i6];
    int s7 = csr_src[i7];
    float2 f0 = __half22float2(ktb[(size_t)s0 * 128]);
    float2 f1 = __half22float2(ktb[(size_t)s1 * 128]);
    float2 f2 = __half22float2(ktb[(size_t)s2 * 128]);
    float2 f3 = __half22float2(ktb[(size_t)s3 * 128]);
    float2 f4 = __half22float2(ktb[(size_t)s4 * 128]);
    float2 f5 = __half22float2(ktb[(size_t)s5 * 128]);
    float2 f6 = __half22float2(ktb[(size_t)s6 * 128]);
    float2 f7 = __half22float2(ktb[(size_t)s7 * 128]);
    float p0 = red16(f0.x * qv);
    float p1 = red16(f1.x * qv);
    float p2 = red16(f2.x * qv);
    float p3 = red16(f3.x * qv);
    float p4 = red16(f4.x * qv);
    float p5 = red16(f5.x * qv);
    float p6 = red16(f6.x * qv);
    float p7 = red16(f7.x * qv);
    float w0 = __expf(p0);
    float w1 = (e + 1 < e1) ? __expf(p1) : 0.f;
    float w2 = (e + 2 < e1) ? __expf(p2) : 0.f;
    float w3 = (e + 3 < e1) ? __expf(p3) : 0.f;
    float w4 = (e + 4 < e1) ? __expf(p4) : 0.f;
    float w5 = (e + 5 < e1) ? __expf(p5) : 0.f;
    float w6 = (e + 6 < e1) ? __expf(p6) : 0.f;
    float w7 = (e + 7 < e1) ? __expf(p7) : 0.f;
    den += ((w0 + w1) + (w2 + w3)) + ((w4 + w5) + (w6 + w7));
    num = fmaf(w0, f0.y, num);
    num = fmaf(w1, f1.y, num);
    num = fmaf(w2, f2.y, num);
    num = fmaf(w3, f3.y, num);
    num = fmaf(w4, f4.y, num);
    num = fmaf(w5, f5.y, num);
    num = fmaf(w6, f6.y, num);
    num = fmaf(w7, f7.y, num);
  }
  agg[(size_t)wid * 64 + lane] = num / (den + 1e-16f);
}

// ---------------- classifier: 64 -> relu(32) -> 2 ----------------------------
__global__ __launch_bounds__(256)
void classifier(const float* __restrict__ h, const float* __restrict__ Wc1,
                const float* __restrict__ bc1, const float* __restrict__ Wc2,
                const float* __restrict__ bc2, float* __restrict__ out, int n)
{
  int row = blockIdx.x * 256 + threadIdx.x;
  if (row >= n) return;
  float hid[32];
#pragma unroll
  for (int j = 0; j < 32; ++j) hid[j] = bc1[j];
  const float* hr = h + (size_t)row * 64;
#pragma unroll 4
  for (int k = 0; k < 64; k += 4) {
    float4 x = *(const float4*)&hr[k];
#pragma unroll
    for (int j = 0; j < 32; ++j) {
      hid[j] += x.x * Wc1[k * 32 + j] + x.y * Wc1[(k + 1) * 32 + j]
              + x.z * Wc1[(k + 2) * 32 + j] + x.w * Wc1[(k + 3) * 32 + j];
    }
  }
  float o0 = bc2[0], o1 = bc2[1];
#pragma unroll
  for (int j = 0; j < 32; ++j) {
    float v = fmaxf(hid[j], 0.f);
    o0 += v * Wc2[j * 2 + 0];
    o1 += v * Wc2[j * 2 + 1];
  }
  *(float2*)&out[(size_t)row * 2] = make_float2(o0, o1);
}

// ---------------------------------------------------------------------------
extern "C" void kernel_launch(void* const* d_in, const int* in_sizes, int n_in,
                              void* d_out, int out_size, void* d_ws, size_t ws_size,
                              hipStream_t stream)
{
  const float* x     = (const float*)d_in[0];
  const int*  eidx   = (const int*)d_in[1];
  const float* Wp    = (const float*)d_in[2];
  const float* bp    = (const float*)d_in[3];
  const float* Wk    = (const float*)d_in[4];
  const float* bk    = (const float*)d_in[5];
  const float* Wq    = (const float*)d_in[6];
  const float* bq    = (const float*)d_in[7];
  const float* Wv    = (const float*)d_in[8];
  const float* bv    = (const float*)d_in[9];
  const float* a_rel = (const float*)d_in[10];
  const float* m_rel = (const float*)d_in[11];
  const float* p_rel = (const float*)d_in[12];
  const float* Wo    = (const float*)d_in[13];
  const float* bo    = (const float*)d_in[14];
  const float* skip  = (const float*)d_in[15];
  const float* Wc1   = (const float*)d_in[16];
  const float* bc1   = (const float*)d_in[17];
  const float* Wc2   = (const float*)d_in[18];
  const float* bc2   = (const float*)d_in[19];
  float* out = (float*)d_out;

  const int N = in_sizes[0] / 768;
  const int E = in_sizes[1] / 2;
  const int* srcIdx = eidx;
  const int* dstIdx = eidx + E;

  char* ws = (char*)d_ws;
  size_t off = 0;
  auto alloc = [&](size_t bytes) -> void* {
    void* p = ws + off;
    off = (off + bytes + 255) & ~(size_t)255;
    return p;
  };
  float* h     = (float*)alloc((size_t)N * 64 * 4);
  float* qkv   = (float*)alloc((size_t)N * 128 * 4);  // [q f32 x64 | half2 x64]
  float* agg   = (float*)alloc((size_t)N * 64 * 4);
  float* Wqkv  = (float*)alloc(2 * 64 * 192 * 4);
  float* bqkv  = (float*)alloc(2 * 192 * 4);
  int* row_ptr = (int*)alloc((size_t)(N + 1) * 4);
  int* cursor  = (int*)alloc((size_t)N * 4);
  int* counts  = (int*)alloc((size_t)N * 4);
  int* blockSums = (int*)alloc(512 * 4);
  int* csr_src = (int*)alloc((size_t)E * 4);
  // split-bf16 chunked weights (h+l interleaved per 64x32 chunk)
  ushort* WtP   = (ushort*)alloc((size_t)64 * 768 * 2 * 2);
  ushort* WtQKV = (ushort*)alloc((size_t)2 * 192 * 64 * 2 * 2);
  ushort* WtO   = (ushort*)alloc((size_t)2 * 64 * 64 * 2 * 2);
  (void)ws_size; (void)n_in; (void)out_size;

  hipMemsetAsync(counts, 0, (size_t)N * 4, stream);

  fold_weights<<<2, 256, 0, stream>>>(Wq, bq, Wk, bk, Wv, bv, a_rel, m_rel, Wqkv, bqkv);

  // transpose + split all GEMM weights into chunked layout (tiny, once)
  prep_weights<<<(768 * 64 + 255) / 256, 256, 0, stream>>>(Wp, 768, 64, WtP);
  for (int l = 0; l < 2; ++l) {
    prep_weights<<<(64 * 192 + 255) / 256, 256, 0, stream>>>(
        Wqkv + l * 64 * 192, 64, 192, WtQKV + (size_t)l * 192 * 64 * 2);
    prep_weights<<<(64 * 64 + 255) / 256, 256, 0, stream>>>(
        Wo + l * 4096, 64, 64, WtO + (size_t)l * 64 * 64 * 2);
  }

  // input projection: h = x @ Wp + bp
  mfma_gemm<768><<<dim3((N + 63) / 64, 1), 256, 0, stream>>>(
      x, 768, WtP, bp, h, 64, N);

  // CSR build (shared by both layers)
  hist_kernel<<<(E + 255) / 256, 256, 0, stream>>>(dstIdx, counts, E);
  int G = (N + 1023) / 1024;
  scanA<<<G, 256, 0, stream>>>(counts, blockSums, N);
  scanB<<<1, 128, 0, stream>>>(blockSums, G, row_ptr, N);
  scanC<<<(N + 255) / 256, 256, 0, stream>>>(counts, blockSums, row_ptr, cursor, N);
  scatter_kernel<<<(E + 255) / 256, 256, 0, stream>>>(srcIdx, dstIdx, cursor, csr_src, E);

  for (int l = 0; l < 2; ++l) {
    // fused q|kt|vt projection with fp16 pack: [N,64] @ [64,192] -> [N,128dw]
    mfma_gemm_k64<3, 2><<<(N + 63) / 64, 256, 0, stream>>>(
        h, WtQKV + (size_t)l * 192 * 64 * 2, bqkv + l * 192,
        nullptr, nullptr, qkv, 128, N);
    // attention + aggregation
    edge_agg<<<(N + 3) / 4, 256, 0, stream>>>(qkv, row_ptr, csr_src, p_rel + l * 4, agg, N);
    // out = relu(g*(gelu(agg)@Wo + bo) + (1-g)*h), in-place into h
    mfma_gemm_k64<1, 1><<<(N + 63) / 64, 256, 0, stream>>>(
        agg, WtO + (size_t)l * 64 * 64 * 2, bo + l * 64, h, skip + l, h, 64, N);
  }

  classifier<<<(N + 255) / 256, 256, 0, stream>>>(h, Wc1, bc1, Wc2, bc2, out, N);
}

// Round 5
// 906.496 us; speedup vs baseline: 1.1811x; 1.0346x over previous
//
#include <hip/hip_runtime.h>
#include <hip/hip_fp16.h>
#include <math.h>

// ---------------------------------------------------------------------------
// SimpleLESS4FDModel: 2-layer HGT on a homogeneous graph.
// a_rel / m_rel folded into projection weights (inline in prep_all).
// Per edge:  alpha = <kt[src], q[dst]>_head * p_rel / 4 ;
//   agg[dst] = sum_e exp(alpha) * vt[src] / (sum_e exp(alpha) + 1e-16)
// CSR (built once, reused by both layers) makes aggregation atomic-free.
//
// R3: split-bf16 MFMA (ah*bh+ah*bl+al*bh).  R5: kt/vt one-load-per-edge.
// R8 (R4 bench, 938us): kt/vt packed fp16 half2 -> ONE dword/lane/edge.
// R9 (this): (a) input GEMM BK=64 (12 super-chunks, half the barriers,
//   24 MFMA per stage, 32KB LDS keeps 4 blocks/CU); (b) qkv GEMM split into
//   q-kernel (CB=1, 4 blk/CU) + ktvt-pack kernel (CB=2, 48KB, 3 blk/CU) --
//   reverts R6's CB=3 (64KB LDS, 2 blk/CU occupancy suspect); (c) prep_all:
//   memset+fold+5x prep fused into one grid-stride launch (20 -> 16 launches).
//   edge_agg unchanged (measured good).
// ---------------------------------------------------------------------------

typedef __attribute__((ext_vector_type(8))) short bf16x8;  // 8 bf16 (4 VGPRs)
typedef __attribute__((ext_vector_type(4))) float f32x4;

__device__ __forceinline__ float gelu_t(float x) {
  const float c = 0.7978845608028654f;  // sqrt(2/pi)
  float t = tanhf(c * (x + 0.044715f * x * x * x));
  return 0.5f * x * (1.0f + t);
}

// split fp32 -> bf16 hi (truncate) + bf16 lo (truncate of remainder)
__device__ __forceinline__ void split1(float a, ushort& h, ushort& l) {
  unsigned u = __float_as_uint(a);
  unsigned uh = u & 0xffff0000u;
  float fl = a - __uint_as_float(uh);
  h = (ushort)(uh >> 16);
  l = (ushort)(__float_as_uint(fl) >> 16);
}

// 16-lane rotation-reduce via DPP row_ror (rotations 1,2,4,8 span the cyclic
// group -> every lane ends with the full 16-lane sum). Pure VALU, no DS pipe.
template<int CTRL>
__device__ __forceinline__ float row_ror_add(float v) {
  int r = __builtin_amdgcn_update_dpp(0, __float_as_int(v), CTRL, 0xF, 0xF, true);
  return v + __int_as_float(r);
}
__device__ __forceinline__ float red16(float v) {
  v = row_ror_add<0x121>(v);  // ror 1
  v = row_ror_add<0x122>(v);  // ror 2
  v = row_ror_add<0x124>(v);  // ror 4
  v = row_ror_add<0x128>(v);  // ror 8
  return v;
}

// ---------------- split-bf16 MFMA GEMM, K=768 streaming, BK=64 ---------------
// out[r, c] = A[r,:] @ W[:,c] + bias[c], C=64. Block: 256 thr = 4 waves,
// 64 rows/block. LDS per super-chunk (64 k): sA/sB = [sub(2)][h|l][64][32].
// Wt layout: per 32-k chunk ch32: 4096 ushorts = [h: c(64) x k(32)] ++ [l...].
// Super-chunk ch = chunks 2ch,2ch+1 = 16KB contiguous.
template<int K>
__global__ __launch_bounds__(256, 4)
void mfma_gemm(const float* __restrict__ A, int ldA,
               const ushort* __restrict__ Wt,
               const float* __restrict__ bias,
               float* __restrict__ outp, int ldOut, int nRows)
{
  constexpr int NSC = K / 64;  // 12 super-chunks
  __shared__ ushort sA[8192];
  __shared__ ushort sB[8192];
  const int tid = threadIdx.x;
  const int lane = tid & 63;
  const int wv = tid >> 6;
  const int m = lane & 15;   // A row / B col / C col within tile
  const int q = lane >> 4;   // quad
  const int row0 = blockIdx.x * 64;

  // staging roles: thread t stages A row (t>>2), k-quarter (t&3)*16 (64 B)
  const int srow = tid >> 2;
  const int sq = tid & 3;
  const int sub = sq >> 1;              // 32-k sub-chunk
  const int koff = (sq & 1) * 16;       // k offset within sub-chunk
  int gr = row0 + srow; if (gr >= nRows) gr = nRows - 1;  // clamp; masked at store
  const float* aBase = A + (size_t)gr * ldA + sq * 16;
  const float4* wBase = (const float4*)Wt;

  f32x4 acc[4];
#pragma unroll
  for (int ct = 0; ct < 4; ++ct) acc[ct] = (f32x4){0.f, 0.f, 0.f, 0.f};

  // prefetch super-chunk 0 A into registers
  float4 a0 = *(const float4*)(aBase + 0);
  float4 a1 = *(const float4*)(aBase + 4);
  float4 a2 = *(const float4*)(aBase + 8);
  float4 a3 = *(const float4*)(aBase + 12);

#pragma clang loop unroll(disable)
  for (int ch = 0; ch < NSC; ++ch) {
    // B for current super-chunk (16 KB; L2-hot weight)
    float4 b0 = wBase[ch * 1024 + tid * 4 + 0];
    float4 b1 = wBase[ch * 1024 + tid * 4 + 1];
    float4 b2 = wBase[ch * 1024 + tid * 4 + 2];
    float4 b3 = wBase[ch * 1024 + tid * 4 + 3];
    float4 na0 = a0, na1 = a1, na2 = a2, na3 = a3;
    if (ch + 1 < NSC) {  // depth-1 A prefetch
      na0 = *(const float4*)(aBase + (ch + 1) * 64 + 0);
      na1 = *(const float4*)(aBase + (ch + 1) * 64 + 4);
      na2 = *(const float4*)(aBase + (ch + 1) * 64 + 8);
      na3 = *(const float4*)(aBase + (ch + 1) * 64 + 12);
    }
    // split current A (16 floats: k = sq*16 + 0..15)
    float av[16] = {a0.x, a0.y, a0.z, a0.w, a1.x, a1.y, a1.z, a1.w,
                    a2.x, a2.y, a2.z, a2.w, a3.x, a3.y, a3.z, a3.w};
    bf16x8 vh0, vl0, vh1, vl1;
#pragma unroll
    for (int j = 0; j < 8; ++j) {
      ushort h, l; split1(av[j], h, l);
      vh0[j] = (short)h; vl0[j] = (short)l;
    }
#pragma unroll
    for (int j = 0; j < 8; ++j) {
      ushort h, l; split1(av[8 + j], h, l);
      vh1[j] = (short)h; vl1[j] = (short)l;
    }
    __syncthreads();  // previous chunk's LDS reads complete before overwrite
    {
      ushort* sAp = sA + sub * 4096 + srow * 32 + koff;
      *(bf16x8*)(sAp) = vh0;
      *(bf16x8*)(sAp + 8) = vh1;
      *(bf16x8*)(sAp + 2048) = vl0;
      *(bf16x8*)(sAp + 2048 + 8) = vl1;
    }
    ((float4*)sB)[tid * 4 + 0] = b0;
    ((float4*)sB)[tid * 4 + 1] = b1;
    ((float4*)sB)[tid * 4 + 2] = b2;
    ((float4*)sB)[tid * 4 + 3] = b3;
    __syncthreads();
    const int fo = (wv * 16 + m) * 32 + q * 8;
    bf16x8 ah0 = *(const bf16x8*)(sA + fo);
    bf16x8 al0 = *(const bf16x8*)(sA + 2048 + fo);
    bf16x8 ah1 = *(const bf16x8*)(sA + 4096 + fo);
    bf16x8 al1 = *(const bf16x8*)(sA + 4096 + 2048 + fo);
#pragma unroll
    for (int ct = 0; ct < 4; ++ct) {
      const int bo = (ct * 16 + m) * 32 + q * 8;
      bf16x8 bh0 = *(const bf16x8*)(sB + bo);
      bf16x8 bl0 = *(const bf16x8*)(sB + 2048 + bo);
      acc[ct] = __builtin_amdgcn_mfma_f32_16x16x32_bf16(ah0, bh0, acc[ct], 0, 0, 0);
      acc[ct] = __builtin_amdgcn_mfma_f32_16x16x32_bf16(ah0, bl0, acc[ct], 0, 0, 0);
      acc[ct] = __builtin_amdgcn_mfma_f32_16x16x32_bf16(al0, bh0, acc[ct], 0, 0, 0);
      bf16x8 bh1 = *(const bf16x8*)(sB + 4096 + bo);
      bf16x8 bl1 = *(const bf16x8*)(sB + 4096 + 2048 + bo);
      acc[ct] = __builtin_amdgcn_mfma_f32_16x16x32_bf16(ah1, bh1, acc[ct], 0, 0, 0);
      acc[ct] = __builtin_amdgcn_mfma_f32_16x16x32_bf16(ah1, bl1, acc[ct], 0, 0, 0);
      acc[ct] = __builtin_amdgcn_mfma_f32_16x16x32_bf16(al1, bh1, acc[ct], 0, 0, 0);
    }
    a0 = na0; a1 = na1; a2 = na2; a3 = na3;
  }

  // epilogue: C/D layout col = lane&15 (=m), row = quad*4 + reg  [m89-verified]
#pragma unroll
  for (int ct = 0; ct < 4; ++ct) {
    int c = ct * 16 + m;
    float b = bias[c];
#pragma unroll
    for (int i = 0; i < 4; ++i) {
      int r = row0 + wv * 16 + q * 4 + i;
      if (r < nRows) outp[(size_t)r * ldOut + c] = acc[ct][i] + b;
    }
  }
}

// ---------------- flat K=64 GEMM: whole problem staged once, ONE barrier -----
// A is [nRows,64] fp32. Wt holds CB col-blocks in the chunked layout.
// EPI: 0 = plain(+bias), 1 = gelu(A) + skip epilogue, 2 = ktvt fp16 pack
//   (CB==2: acc[0]=kt, acc[1]=vt -> half2 at dword 64+c of a 128-dword row).
template<int CB, int EPI>
__global__ __launch_bounds__(256, (CB == 1) ? 4 : 3)
void mfma_gemm_k64(const float* __restrict__ A,
                   const ushort* __restrict__ Wt,
                   const float* __restrict__ bias,
                   const float* __restrict__ Hprev,
                   const float* __restrict__ skipPtr,
                   float* __restrict__ outp, int ldOut, int nRows)
{
  __shared__ ushort sA[2 * 4096];        // [ch][h(2048) ++ l(2048)]
  __shared__ ushort sB[CB][2 * 4096];
  const int tid = threadIdx.x;
  const int lane = tid & 63;
  const int wv = tid >> 6;
  const int m = lane & 15;
  const int q = lane >> 4;
  const int row0 = blockIdx.x * 64;
  const int srow = tid >> 2;
  const int skoff = (tid & 3) * 8;
  int gr = row0 + srow; if (gr >= nRows) gr = nRows - 1;
  const float* aBase = A + (size_t)gr * 64 + skoff;
  const float4* wBase = (const float4*)Wt;

  // issue ALL global loads up front
  float4 a0 = *(const float4*)(aBase + 0);
  float4 a1 = *(const float4*)(aBase + 4);
  float4 a2 = *(const float4*)(aBase + 32);
  float4 a3 = *(const float4*)(aBase + 36);
  float4 bb0[CB], bb1[CB], bb2[CB], bb3[CB];
#pragma unroll
  for (int cb = 0; cb < CB; ++cb) {
    bb0[cb] = wBase[(size_t)(cb * 2 + 0) * 512 + tid * 2];
    bb1[cb] = wBase[(size_t)(cb * 2 + 0) * 512 + tid * 2 + 1];
    bb2[cb] = wBase[(size_t)(cb * 2 + 1) * 512 + tid * 2];
    bb3[cb] = wBase[(size_t)(cb * 2 + 1) * 512 + tid * 2 + 1];
  }

  // split + store A (both 32-k chunks)
  {
    float av[16] = {a0.x, a0.y, a0.z, a0.w, a1.x, a1.y, a1.z, a1.w,
                    a2.x, a2.y, a2.z, a2.w, a3.x, a3.y, a3.z, a3.w};
    if (EPI == 1) {
#pragma unroll
      for (int j = 0; j < 16; ++j) av[j] = gelu_t(av[j]);
    }
    bf16x8 vh0, vl0, vh1, vl1;
#pragma unroll
    for (int j = 0; j < 8; ++j) {
      ushort h, l; split1(av[j], h, l);
      vh0[j] = (short)h; vl0[j] = (short)l;
    }
#pragma unroll
    for (int j = 0; j < 8; ++j) {
      ushort h, l; split1(av[8 + j], h, l);
      vh1[j] = (short)h; vl1[j] = (short)l;
    }
    *(bf16x8*)(sA + srow * 32 + skoff) = vh0;
    *(bf16x8*)(sA + 2048 + srow * 32 + skoff) = vl0;
    *(bf16x8*)(sA + 4096 + srow * 32 + skoff) = vh1;
    *(bf16x8*)(sA + 4096 + 2048 + srow * 32 + skoff) = vl1;
  }
#pragma unroll
  for (int cb = 0; cb < CB; ++cb) {
    ((float4*)(sB[cb]))[tid * 2] = bb0[cb];
    ((float4*)(sB[cb]))[tid * 2 + 1] = bb1[cb];
    ((float4*)(sB[cb] + 4096))[tid * 2] = bb2[cb];
    ((float4*)(sB[cb] + 4096))[tid * 2 + 1] = bb3[cb];
  }
  __syncthreads();

  f32x4 acc[CB][4];
#pragma unroll
  for (int cb = 0; cb < CB; ++cb)
#pragma unroll
    for (int ct = 0; ct < 4; ++ct) acc[cb][ct] = (f32x4){0.f, 0.f, 0.f, 0.f};

  bf16x8 ah0 = *(const bf16x8*)(sA + (wv * 16 + m) * 32 + q * 8);
  bf16x8 al0 = *(const bf16x8*)(sA + 2048 + (wv * 16 + m) * 32 + q * 8);
  bf16x8 ah1 = *(const bf16x8*)(sA + 4096 + (wv * 16 + m) * 32 + q * 8);
  bf16x8 al1 = *(const bf16x8*)(sA + 4096 + 2048 + (wv * 16 + m) * 32 + q * 8);
#pragma unroll
  for (int cb = 0; cb < CB; ++cb) {
#pragma unroll
    for (int ct = 0; ct < 4; ++ct) {
      bf16x8 bh0 = *(const bf16x8*)(sB[cb] + (ct * 16 + m) * 32 + q * 8);
      bf16x8 bl0 = *(const bf16x8*)(sB[cb] + 2048 + (ct * 16 + m) * 32 + q * 8);
      acc[cb][ct] = __builtin_amdgcn_mfma_f32_16x16x32_bf16(ah0, bh0, acc[cb][ct], 0, 0, 0);
      acc[cb][ct] = __builtin_amdgcn_mfma_f32_16x16x32_bf16(ah0, bl0, acc[cb][ct], 0, 0, 0);
      acc[cb][ct] = __builtin_amdgcn_mfma_f32_16x16x32_bf16(al0, bh0, acc[cb][ct], 0, 0, 0);
      bf16x8 bh1 = *(const bf16x8*)(sB[cb] + 4096 + (ct * 16 + m) * 32 + q * 8);
      bf16x8 bl1 = *(const bf16x8*)(sB[cb] + 4096 + 2048 + (ct * 16 + m) * 32 + q * 8);
      acc[cb][ct] = __builtin_amdgcn_mfma_f32_16x16x32_bf16(ah1, bh1, acc[cb][ct], 0, 0, 0);
      acc[cb][ct] = __builtin_amdgcn_mfma_f32_16x16x32_bf16(ah1, bl1, acc[cb][ct], 0, 0, 0);
      acc[cb][ct] = __builtin_amdgcn_mfma_f32_16x16x32_bf16(al1, bh1, acc[cb][ct], 0, 0, 0);
    }
  }

  if (EPI == 2) {
    // kt = acc[0], vt = acc[1]; packed half2 at dword 64+c of 128-dword row
#pragma unroll
    for (int ct = 0; ct < 4; ++ct) {
      int c = ct * 16 + m;
      float bk_ = bias[c], bv_ = bias[64 + c];
#pragma unroll
      for (int i = 0; i < 4; ++i) {
        int r = row0 + wv * 16 + q * 4 + i;
        if (r < nRows) {
          __half2 kv = __floats2half2_rn(acc[0][ct][i] + bk_, acc[1][ct][i] + bv_);
          *((__half2*)outp + (size_t)r * 128 + 64 + c) = kv;
        }
      }
    }
  } else {
    float g = 0.f, gi = 0.f;
    if (EPI == 1) { g = 1.0f / (1.0f + __expf(-skipPtr[0])); gi = 1.0f - g; }
#pragma unroll
    for (int cb = 0; cb < CB; ++cb) {
#pragma unroll
      for (int ct = 0; ct < 4; ++ct) {
        int c = cb * 64 + ct * 16 + m;
        float b = bias[c];
#pragma unroll
        for (int i = 0; i < 4; ++i) {
          int r = row0 + wv * 16 + q * 4 + i;
          if (r < nRows) {
            float o = acc[cb][ct][i] + b;
            if (EPI == 1) {
              float hp = Hprev[(size_t)r * 64 + c];
              o = fmaxf(g * o + gi * hp, 0.f);
            }
            outp[(size_t)r * ldOut + c] = o;
          }
        }
      }
    }
  }
}

// ---------------- prep_all: fold + transpose/split + counts zero, ONE launch -
// Item space: [0,49152) WtP | [.,+24576) WtQKV (fold inline) | [.,+8192) WtO
//             | [.,+384) bqkv fold | [., +n) counts zero
__global__ void prep_all(const float* __restrict__ Wp,
                         const float* __restrict__ Wq, const float* __restrict__ bq,
                         const float* __restrict__ Wk, const float* __restrict__ bk,
                         const float* __restrict__ Wv, const float* __restrict__ bv,
                         const float* __restrict__ a_rel, const float* __restrict__ m_rel,
                         const float* __restrict__ Wo,
                         ushort* __restrict__ WtP, ushort* __restrict__ WtQKV,
                         ushort* __restrict__ WtO, float* __restrict__ bqkv,
                         int* __restrict__ counts, int n)
{
  int i = blockIdx.x * 256 + threadIdx.x;
  if (i < 49152) {
    // WtP from Wp [768][64]
    int k = i >> 6, c = i & 63;
    ushort h, l; split1(Wp[i], h, l);
    size_t base = (size_t)(k >> 5) * 4096;
    WtP[base + c * 32 + (k & 31)] = h;
    WtP[base + 2048 + c * 32 + (k & 31)] = l;
  } else if (i < 49152 + 24576) {
    int j = i - 49152;
    int l_ = j / 12288; j -= l_ * 12288;
    int k = j / 192, c = j - k * 192;
    float val;
    if (c < 64) {
      val = Wq[l_ * 4096 + k * 64 + c];
    } else if (c < 128) {
      int cc = c - 64, hh = cc >> 4, f = cc & 15;
      const float* wk_ = Wk + l_ * 4096 + k * 64 + hh * 16;
      const float* ar = a_rel + l_ * 1024 + hh * 256 + f;
      float s = 0.f;
      for (int d = 0; d < 16; ++d) s += wk_[d] * ar[d * 16];
      val = s;
    } else {
      int cc = c - 128, hh = cc >> 4, f = cc & 15;
      const float* wv_ = Wv + l_ * 4096 + k * 64 + hh * 16;
      const float* mr = m_rel + l_ * 1024 + hh * 256 + f;
      float s = 0.f;
      for (int d = 0; d < 16; ++d) s += wv_[d] * mr[d * 16];
      val = s;
    }
    ushort h, l; split1(val, h, l);
    int cb = c >> 6, cc2 = c & 63;
    size_t base = ((size_t)l_ * 6 + cb * 2 + (k >> 5)) * 4096;
    WtQKV[base + cc2 * 32 + (k & 31)] = h;
    WtQKV[base + 2048 + cc2 * 32 + (k & 31)] = l;
  } else if (i < 49152 + 24576 + 8192) {
    int j = i - 49152 - 24576;
    int l_ = j >> 12; j &= 4095;
    int k = j >> 6, c = j & 63;
    ushort h, l; split1(Wo[l_ * 4096 + j], h, l);
    size_t base = ((size_t)l_ * 2 + (k >> 5)) * 4096;
    WtO[base + c * 32 + (k & 31)] = h;
    WtO[base + 2048 + c * 32 + (k & 31)] = l;
  } else if (i < 49152 + 24576 + 8192 + 384) {
    int j = i - 49152 - 24576 - 8192;
    int l_ = j / 192, c = j - l_ * 192;
    float val;
    if (c < 64) {
      val = bq[l_ * 64 + c];
    } else if (c < 128) {
      int cc = c - 64, hh = cc >> 4, f = cc & 15;
      const float* bk_ = bk + l_ * 64 + hh * 16;
      const float* ar = a_rel + l_ * 1024 + hh * 256 + f;
      float s = 0.f;
      for (int d = 0; d < 16; ++d) s += bk_[d] * ar[d * 16];
      val = s;
    } else {
      int cc = c - 128, hh = cc >> 4, f = cc & 15;
      const float* bv_ = bv + l_ * 64 + hh * 16;
      const float* mr = m_rel + l_ * 1024 + hh * 256 + f;
      float s = 0.f;
      for (int d = 0; d < 16; ++d) s += bv_[d] * mr[d * 16];
      val = s;
    }
    bqkv[l_ * 192 + c] = val;
  } else if (i < 49152 + 24576 + 8192 + 384 + n) {
    counts[i - (49152 + 24576 + 8192 + 384)] = 0;
  }
}

// ---------------- CSR construction -------------------------------------------
__global__ void hist_kernel(const int* __restrict__ dst, int* __restrict__ counts, int E) {
  int e = blockIdx.x * 256 + threadIdx.x;
  if (e < E) atomicAdd(&counts[dst[e]], 1);
}

__global__ __launch_bounds__(256)
void scanA(int* __restrict__ counts, int* __restrict__ blockSums, int n) {
  __shared__ int sd[256];
  int tid = threadIdx.x;
  int base = blockIdx.x * 1024 + tid * 4;
  int v[4];
#pragma unroll
  for (int j = 0; j < 4; ++j) v[j] = (base + j < n) ? counts[base + j] : 0;
  int t = v[0] + v[1] + v[2] + v[3];
  sd[tid] = t; __syncthreads();
  for (int offm = 1; offm < 256; offm <<= 1) {
    int adj = (tid >= offm) ? sd[tid - offm] : 0;
    __syncthreads();
    sd[tid] += adj;
    __syncthreads();
  }
  int run = sd[tid] - t;  // exclusive prefix for this thread
#pragma unroll
  for (int j = 0; j < 4; ++j) {
    if (base + j < n) counts[base + j] = run;
    run += v[j];
  }
  if (tid == 255) blockSums[blockIdx.x] = sd[255];
}

__global__ void scanB(int* __restrict__ blockSums, int G, int* __restrict__ row_ptr, int n) {
  __shared__ int sd[128];
  int tid = threadIdx.x;
  int t = (tid < G) ? blockSums[tid] : 0;
  sd[tid] = t; __syncthreads();
  for (int offm = 1; offm < 128; offm <<= 1) {
    int adj = (tid >= offm) ? sd[tid - offm] : 0;
    __syncthreads();
    sd[tid] += adj;
    __syncthreads();
  }
  if (tid < G) blockSums[tid] = sd[tid] - t;
  if (tid == 127) row_ptr[n] = sd[127];  // total = E
}

__global__ void scanC(const int* __restrict__ counts, const int* __restrict__ blockSums,
                      int* __restrict__ row_ptr, int* __restrict__ cursor, int n) {
  int idx = blockIdx.x * 256 + threadIdx.x;
  if (idx < n) {
    int v = counts[idx] + blockSums[idx >> 10];
    row_ptr[idx] = v;
    cursor[idx] = v;
  }
}

__global__ void scatter_kernel(const int* __restrict__ src, const int* __restrict__ dst,
                               int* __restrict__ cursor, int* __restrict__ csr_src, int E) {
  int e = blockIdx.x * 256 + threadIdx.x;
  if (e < E) {
    int d = dst[e];
    int pos = atomicAdd(&cursor[d], 1);
    csr_src[pos] = src[e];
  }
}

// ---------------- fused attention aggregation: one wave per dst node ----------
// lane = head*16 + f. qkv row: [q fp32 x64 | half2(kt,vt) x64], 128 dwords.
// 8-wide masked edge unroll (duplicate tail gathers are L1 hits); ONE dword
// gather per lane per edge; DPP rotation-reduce (VALU) for the 16-lane dot.
__global__ __launch_bounds__(256)
void edge_agg(const float* __restrict__ qkv, const int* __restrict__ row_ptr,
              const int* __restrict__ csr_src, const float* __restrict__ p_rel,
              float* __restrict__ agg, int n)
{
  int wid = blockIdx.x * 4 + (threadIdx.x >> 6);
  if (wid >= n) return;
  int lane = threadIdx.x & 63;
  int head = lane >> 4;
  float pr = p_rel[head] * 0.25f;  // p_rel / sqrt(D), D=16
  float qv = qkv[(size_t)wid * 128 + lane] * pr;  // prescaled
  int e0 = __builtin_amdgcn_readfirstlane(row_ptr[wid]);
  int e1 = __builtin_amdgcn_readfirstlane(row_ptr[wid + 1]);
  const __half2* ktb = (const __half2*)qkv + 64 + lane;
  float num = 0.f, den = 0.f;
  for (int e = e0; e < e1; e += 8) {
    int last = e1 - 1;
    int i1 = (e + 1 < e1) ? e + 1 : last;
    int i2 = (e + 2 < e1) ? e + 2 : last;
    int i3 = (e + 3 < e1) ? e + 3 : last;
    int i4 = (e + 4 < e1) ? e + 4 : last;
    int i5 = (e + 5 < e1) ? e + 5 : last;
    int i6 = (e + 6 < e1) ? e + 6 : last;
    int i7 = (e + 7 < e1) ? e + 7 : last;
    int s0 = csr_src[e];
    int s1 = csr_src[i1];
    int s2 = csr_src[i2];
    int s3 = csr_src[i3];
    int s4 = csr_src[i4];
    int s5 = csr_src[i5];
    int s6 = csr_src[i6];
    int s7 = csr_src[i7];
    float2 f0 = __half22float2(ktb[(size_t)s0 * 128]);
    float2 f1 = __half22float2(ktb[(size_t)s1 * 128]);
    float2 f2 = __half22float2(ktb[(size_t)s2 * 128]);
    float2 f3 = __half22float2(ktb[(size_t)s3 * 128]);
    float2 f4 = __half22float2(ktb[(size_t)s4 * 128]);
    float2 f5 = __half22float2(ktb[(size_t)s5 * 128]);
    float2 f6 = __half22float2(ktb[(size_t)s6 * 128]);
    float2 f7 = __half22float2(ktb[(size_t)s7 * 128]);
    float p0 = red16(f0.x * qv);
    float p1 = red16(f1.x * qv);
    float p2 = red16(f2.x * qv);
    float p3 = red16(f3.x * qv);
    float p4 = red16(f4.x * qv);
    float p5 = red16(f5.x * qv);
    float p6 = red16(f6.x * qv);
    float p7 = red16(f7.x * qv);
    float w0 = __expf(p0);
    float w1 = (e + 1 < e1) ? __expf(p1) : 0.f;
    float w2 = (e + 2 < e1) ? __expf(p2) : 0.f;
    float w3 = (e + 3 < e1) ? __expf(p3) : 0.f;
    float w4 = (e + 4 < e1) ? __expf(p4) : 0.f;
    float w5 = (e + 5 < e1) ? __expf(p5) : 0.f;
    float w6 = (e + 6 < e1) ? __expf(p6) : 0.f;
    float w7 = (e + 7 < e1) ? __expf(p7) : 0.f;
    den += ((w0 + w1) + (w2 + w3)) + ((w4 + w5) + (w6 + w7));
    num = fmaf(w0, f0.y, num);
    num = fmaf(w1, f1.y, num);
    num = fmaf(w2, f2.y, num);
    num = fmaf(w3, f3.y, num);
    num = fmaf(w4, f4.y, num);
    num = fmaf(w5, f5.y, num);
    num = fmaf(w6, f6.y, num);
    num = fmaf(w7, f7.y, num);
  }
  agg[(size_t)wid * 64 + lane] = num / (den + 1e-16f);
}

// ---------------- classifier: 64 -> relu(32) -> 2 ----------------------------
__global__ __launch_bounds__(256)
void classifier(const float* __restrict__ h, const float* __restrict__ Wc1,
                const float* __restrict__ bc1, const float* __restrict__ Wc2,
                const float* __restrict__ bc2, float* __restrict__ out, int n)
{
  int row = blockIdx.x * 256 + threadIdx.x;
  if (row >= n) return;
  float hid[32];
#pragma unroll
  for (int j = 0; j < 32; ++j) hid[j] = bc1[j];
  const float* hr = h + (size_t)row * 64;
#pragma unroll 4
  for (int k = 0; k < 64; k += 4) {
    float4 x = *(const float4*)&hr[k];
#pragma unroll
    for (int j = 0; j < 32; ++j) {
      hid[j] += x.x * Wc1[k * 32 + j] + x.y * Wc1[(k + 1) * 32 + j]
              + x.z * Wc1[(k + 2) * 32 + j] + x.w * Wc1[(k + 3) * 32 + j];
    }
  }
  float o0 = bc2[0], o1 = bc2[1];
#pragma unroll
  for (int j = 0; j < 32; ++j) {
    float v = fmaxf(hid[j], 0.f);
    o0 += v * Wc2[j * 2 + 0];
    o1 += v * Wc2[j * 2 + 1];
  }
  *(float2*)&out[(size_t)row * 2] = make_float2(o0, o1);
}

// ---------------------------------------------------------------------------
extern "C" void kernel_launch(void* const* d_in, const int* in_sizes, int n_in,
                              void* d_out, int out_size, void* d_ws, size_t ws_size,
                              hipStream_t stream)
{
  const float* x     = (const float*)d_in[0];
  const int*  eidx   = (const int*)d_in[1];
  const float* Wp    = (const float*)d_in[2];
  const float* bp    = (const float*)d_in[3];
  const float* Wk    = (const float*)d_in[4];
  const float* bk    = (const float*)d_in[5];
  const float* Wq    = (const float*)d_in[6];
  const float* bq    = (const float*)d_in[7];
  const float* Wv    = (const float*)d_in[8];
  const float* bv    = (const float*)d_in[9];
  const float* a_rel = (const float*)d_in[10];
  const float* m_rel = (const float*)d_in[11];
  const float* p_rel = (const float*)d_in[12];
  const float* Wo    = (const float*)d_in[13];
  const float* bo    = (const float*)d_in[14];
  const float* skip  = (const float*)d_in[15];
  const float* Wc1   = (const float*)d_in[16];
  const float* bc1   = (const float*)d_in[17];
  const float* Wc2   = (const float*)d_in[18];
  const float* bc2   = (const float*)d_in[19];
  float* out = (float*)d_out;

  const int N = in_sizes[0] / 768;
  const int E = in_sizes[1] / 2;
  const int* srcIdx = eidx;
  const int* dstIdx = eidx + E;

  char* ws = (char*)d_ws;
  size_t off = 0;
  auto alloc = [&](size_t bytes) -> void* {
    void* p = ws + off;
    off = (off + bytes + 255) & ~(size_t)255;
    return p;
  };
  float* h     = (float*)alloc((size_t)N * 64 * 4);
  float* qkv   = (float*)alloc((size_t)N * 128 * 4);  // [q f32 x64 | half2 x64]
  float* agg   = (float*)alloc((size_t)N * 64 * 4);
  float* bqkv  = (float*)alloc(2 * 192 * 4);
  int* row_ptr = (int*)alloc((size_t)(N + 1) * 4);
  int* cursor  = (int*)alloc((size_t)N * 4);
  int* counts  = (int*)alloc((size_t)N * 4);
  int* blockSums = (int*)alloc(512 * 4);
  int* csr_src = (int*)alloc((size_t)E * 4);
  // split-bf16 chunked weights (h+l per 64x32 chunk)
  ushort* WtP   = (ushort*)alloc((size_t)64 * 768 * 2 * 2);
  ushort* WtQKV = (ushort*)alloc((size_t)2 * 192 * 64 * 2 * 2);
  ushort* WtO   = (ushort*)alloc((size_t)2 * 64 * 64 * 2 * 2);
  (void)ws_size; (void)n_in; (void)out_size;

  // all weight prep + counts zeroing in ONE launch
  int prepTotal = 49152 + 24576 + 8192 + 384 + N;
  prep_all<<<(prepTotal + 255) / 256, 256, 0, stream>>>(
      Wp, Wq, bq, Wk, bk, Wv, bv, a_rel, m_rel, Wo,
      WtP, WtQKV, WtO, bqkv, counts, N);

  // input projection: h = x @ Wp + bp
  mfma_gemm<768><<<(N + 63) / 64, 256, 0, stream>>>(
      x, 768, WtP, bp, h, 64, N);

  // CSR build (shared by both layers)
  hist_kernel<<<(E + 255) / 256, 256, 0, stream>>>(dstIdx, counts, E);
  int G = (N + 1023) / 1024;
  scanA<<<G, 256, 0, stream>>>(counts, blockSums, N);
  scanB<<<1, 128, 0, stream>>>(blockSums, G, row_ptr, N);
  scanC<<<(N + 255) / 256, 256, 0, stream>>>(counts, blockSums, row_ptr, cursor, N);
  scatter_kernel<<<(E + 255) / 256, 256, 0, stream>>>(srcIdx, dstIdx, cursor, csr_src, E);

  for (int l = 0; l < 2; ++l) {
    // q plane: [N,64] @ [64,64] -> fp32 dwords 0..63 of 128-dword row
    mfma_gemm_k64<1, 0><<<(N + 63) / 64, 256, 0, stream>>>(
        h, WtQKV + (size_t)l * 24576, bqkv + l * 192,
        nullptr, nullptr, qkv, 128, N);
    // kt+vt planes with fp16 pack -> half2 dwords 64..127
    mfma_gemm_k64<2, 2><<<(N + 63) / 64, 256, 0, stream>>>(
        h, WtQKV + (size_t)l * 24576 + 8192, bqkv + l * 192 + 64,
        nullptr, nullptr, qkv, 128, N);
    // attention + aggregation
    edge_agg<<<(N + 3) / 4, 256, 0, stream>>>(qkv, row_ptr, csr_src, p_rel + l * 4, agg, N);
    // out = relu(g*(gelu(agg)@Wo + bo) + (1-g)*h), in-place into h
    mfma_gemm_k64<1, 1><<<(N + 63) / 64, 256, 0, stream>>>(
        agg, WtO + (size_t)l * 8192, bo + l * 64, h, skip + l, h, 64, N);
  }

  classifier<<<(N + 255) / 256, 256, 0, stream>>>(h, Wc1, bc1, Wc2, bc2, out, N);
}